// Round 13
// baseline (259.732 us; speedup 1.0000x reference)
//
#include <hip/hip_runtime.h>

typedef __attribute__((ext_vector_type(4))) float f32x4;
typedef __attribute__((ext_vector_type(8))) short bf16x8;
typedef __attribute__((ext_vector_type(4))) unsigned int u32x4;

__device__ __forceinline__ unsigned short f2bf(float f) {
    union { float f; unsigned int u; } x; x.f = f;
    unsigned int u = x.u;
    return (unsigned short)((u + 0x7FFFu + ((u >> 16) & 1u)) >> 16);
}
__device__ __forceinline__ float bf2f(unsigned short b) {
    union { unsigned int u; float f; } x; x.u = ((unsigned int)b) << 16;
    return x.f;
}
__device__ __forceinline__ float u2f(unsigned int u) {
    union { unsigned int u; float f; } x; x.u = u; return x.f;
}

// blocked layout (row r, ch k), 128-row blocks: ((r>>7)*8 + (k>>5))*4096 + (r&127)*32 + (k&31)
// LDS tiles: 16B-chunk XOR swizzle, chunk c of row r at c ^ ((r>>1)&3); staging pre-swizzles
// the per-lane GLOBAL source (LDS dest linear); reads use chunk lk ^ ((lrow>>1)&3).
// kv_t layout: [pixel][head][K ch 0-31 | V ch 0-31] bf16 (head-interleaved, 128B per head).

// ---------------- prep: concat W_k|W_v (bf16, blocked) and biases ----------------
__global__ void prep_wkv(const float* __restrict__ Wk, const float* __restrict__ bk,
                         const float* __restrict__ Wv, const float* __restrict__ bv,
                         unsigned short* __restrict__ Wkv, float* __restrict__ bkv) {
    int i = blockIdx.x * 256 + threadIdx.x;
    if (i < 512 * 256) {
        int n = i >> 8, k = i & 255;
        float v = (n < 256) ? Wk[i] : Wv[i - 65536];
        Wkv[((size_t)(n >> 7) * 8 + (k >> 5)) * 4096 + (n & 127) * 32 + (k & 31)] = f2bf(v);
    }
    if (i < 512) bkv[i] = (i < 256) ? bk[i] : bv[i - 256];
}

// ---------------- prep: W_off -> blocked bf16 (rows 0-63 of each kt block) ----------------
__global__ void prep_woff(const float* __restrict__ Woff, unsigned short* __restrict__ Woffp) {
    int n = blockIdx.x, k = threadIdx.x;
    Woffp[(size_t)(k >> 5) * 4096 + n * 32 + (k & 31)] = f2bf(Woff[n * 256 + k]);
}

// ---------------- transpose features [48][256][2816] -> bf16 blocked ----------------
__global__ __launch_bounds__(256) void transpose_feat(const float* __restrict__ src,
                                                      unsigned short* __restrict__ dst) {
    __shared__ float tile[32][33];
    int img = blockIdx.z;
    int p0 = blockIdx.x * 32;   // pixel
    int d0 = blockIdx.y * 32;   // channel
    int tx = threadIdx.x & 31, ty = threadIdx.x >> 5;
    const float* s = src + (size_t)img * 256 * 2816;
#pragma unroll
    for (int i = 0; i < 4; i++) tile[ty + 8 * i][tx] = s[(size_t)(d0 + ty + 8 * i) * 2816 + p0 + tx];
    __syncthreads();
    int m = img * 2816 + p0;
    unsigned short* o = dst + ((size_t)(m >> 7) * 8 + (d0 >> 5)) * 4096 + (m & 127) * 32;
#pragma unroll
    for (int i = 0; i < 4; i++) o[(ty + 8 * i) * 32 + tx] = f2bf(tile[tx][ty + 8 * i]);
}

// ---------------- kv+off projection: 256x64 tile, barrier-free counted-vmcnt K-loop ----------------
// bn 0..7: kv_t (head-interleaved cols) = A @ Wkv^T + bkv (64 original cols per bn)
// bn 8   : Foff[135168][64] fp32 = A @ Woff^T (no bias)
// Block = 256 px x 64 cols; 4 waves, wave w owns px w*64..w*64+63 (wave-private A staging).
// B (64x256, 32KB) staged ONCE pre-loop. A ring: 3 slots x 16KB, depth-2, vmcnt(4).
// LDS 80KB -> 2 blocks/CU.
__global__ __launch_bounds__(256) void gemm_kv2(
    const unsigned short* __restrict__ A,
    const unsigned short* __restrict__ Wkv,
    const unsigned short* __restrict__ Woffp,
    const float* __restrict__ bias,
    unsigned short* __restrict__ C,
    float* __restrict__ Foff) {
    __shared__ __align__(16) unsigned short Bl[16384];    // 32KB: [kt][64r][32c] (swizzled)
    __shared__ __align__(16) unsigned short Ar[3][8192];  // ring: [slot][4 waves][64px][32c] (swizzled)

    const int tid = threadIdx.x, lane = tid & 63, w = tid >> 6;
    const int lrow = lane & 15, lk = lane >> 4;
    const int lsw = (lane >> 2) * 32 + (((lane & 3) ^ ((lane >> 3) & 3)) * 8);
    const int ckx = ((lrow >> 1) & 3);    // read-side chunk xor
    const int bid = blockIdx.x;
    const int wgid = (bid & 7) * 594 + (bid >> 3);  // XCD swizzle (4752 = 8*594)
    const int chunk = wgid / 9, bn = wgid % 9;      // chunk: 256-px group 0..527, bn: 0..8

    const unsigned short* A0 = A + (size_t)chunk * 65536;
    const unsigned short* Bb = (bn < 8)
        ? Wkv + (size_t)(bn >> 1) * 32768 + (bn & 1) * 2048
        : Woffp;
    // wave-private A source/dest offsets
    const int wsrc = (w >> 1) * 32768 + (w & 1) * 2048;  // within A0, add kt*4096
    const int wdst = w * 2048;                           // within a ring slot (shorts)

    // stage B fully: 8 kt x 2KB-chunks; wave w stages kt = 2w, 2w+1 (8 x 1KB loads)
#pragma unroll
    for (int i = 0; i < 8; ++i) {
        int kt = w * 2 + (i >> 2), part = i & 3;
        __builtin_amdgcn_global_load_lds(
            (const __attribute__((address_space(1))) unsigned int*)(Bb + kt * 4096 + part * 512 + lsw),
            (__attribute__((address_space(3))) unsigned int*)&Bl[kt * 2048 + part * 512], 16, 0, 0);
    }

#define STAGE_STEP(S)                                                                        \
    {                                                                                        \
        _Pragma("unroll")                                                                    \
        for (int i = 0; i < 4; ++i) {                                                        \
            __builtin_amdgcn_global_load_lds(                                                \
                (const __attribute__((address_space(1))) unsigned int*)(A0 + wsrc + (S) * 4096 + i * 512 + lsw), \
                (__attribute__((address_space(3))) unsigned int*)&Ar[(S) % 3][wdst + i * 512], 16, 0, 0);        \
        }                                                                                    \
    }

    STAGE_STEP(0) STAGE_STEP(1)
    __syncthreads();   // drains: B + A0,A1 resident

    f32x4 acc[4][4] = {};   // [i][j], wave covers px w*64 + i*16 + ...

    // COMP: wait A(S) -> ds_read frags -> drain own ds_reads -> stage A(S+2) -> MFMAs
#define COMP_STEP(S, NW)                                                                     \
    {                                                                                        \
        asm volatile("s_waitcnt vmcnt(%0)" :: "i"(NW) : "memory");                           \
        bf16x8 bfr[4], af[4];                                                                \
        _Pragma("unroll") for (int j = 0; j < 4; ++j)                                        \
            bfr[j] = *(const bf16x8*)&Bl[(S) * 2048 + (j * 16 + lrow) * 32 + (lk ^ ckx) * 8];\
        _Pragma("unroll") for (int i = 0; i < 4; ++i)                                        \
            af[i] = *(const bf16x8*)&Ar[(S) % 3][wdst + (i * 16 + lrow) * 32 + (lk ^ ckx) * 8]; \
        if ((S) + 2 < 8) {                                                                   \
            asm volatile("s_waitcnt lgkmcnt(0)" ::: "memory");                               \
            STAGE_STEP((S) + 2)                                                              \
        }                                                                                    \
        _Pragma("unroll") for (int i = 0; i < 4; ++i)                                        \
            _Pragma("unroll") for (int j = 0; j < 4; ++j)                                    \
                acc[i][j] = __builtin_amdgcn_mfma_f32_16x16x32_bf16(af[i], bfr[j], acc[i][j], 0, 0, 0); \
    }

    COMP_STEP(0, 63) COMP_STEP(1, 63) COMP_STEP(2, 4) COMP_STEP(3, 4)
    COMP_STEP(4, 4)  COMP_STEP(5, 4)  COMP_STEP(6, 4) COMP_STEP(7, 0)
#undef COMP_STEP
#undef STAGE_STEP

    if (bn < 8) {
        // epilogue: two 128-row passes; acc -> LDS [128][64] bf16 -> 16B stores (head-interleaved)
        unsigned short* Cl = &Ar[0][0];   // 16KB of the 48KB ring
#pragma unroll
        for (int p = 0; p < 2; ++p) {
            __syncthreads();
            if ((w >> 1) == p) {
#pragma unroll
                for (int j = 0; j < 4; ++j) {
                    float bs = bias[bn * 64 + j * 16 + lrow];
#pragma unroll
                    for (int i = 0; i < 4; ++i)
#pragma unroll
                        for (int jj = 0; jj < 4; ++jj)
                            Cl[((w & 1) * 64 + i * 16 + lk * 4 + jj) * 64 + j * 16 + lrow] =
                                f2bf(acc[i][j][jj] + bs);
                }
            }
            __syncthreads();
            // original col g = bn*64 + local; K (bn<4): dst h*64+d; V: dst h*64+32+d
#pragma unroll
            for (int it = 0; it < 4; ++it) {
                int idx = it * 256 + tid;
                int row = idx >> 3, col8 = idx & 7;
                int dstcol = (bn < 4)
                    ? (bn * 2 + (col8 >> 2)) * 64 + (col8 & 3) * 8
                    : ((bn - 4) * 2 + (col8 >> 2)) * 64 + 32 + (col8 & 3) * 8;
                *(f32x4*)(C + (size_t)(chunk * 256 + p * 128 + row) * 512 + dstcol) =
                    *(const f32x4*)&Cl[row * 64 + col8 * 8];
            }
        }
    } else {
        // Foff epilogue: fp32 direct stores (no bias)
#pragma unroll
        for (int i = 0; i < 4; ++i)
#pragma unroll
            for (int j = 0; j < 4; ++j)
#pragma unroll
                for (int jj = 0; jj < 4; ++jj) {
                    int m = chunk * 256 + w * 64 + i * 16 + lk * 4 + jj;
                    Foff[(size_t)m * 64 + j * 16 + lrow] = acc[i][j][jj];
                }
    }
}

// ---------------- sample_offs: project points, bilinear-blend Foff, add qWoff ----------------
__global__ __launch_bounds__(384) void sample_offs(
    const float* __restrict__ points, const float* __restrict__ camM,
    const float* __restrict__ camb, const float* __restrict__ Foff,
    const float* __restrict__ qWoff,
    float* __restrict__ offs, float* __restrict__ pxy) {
    int bk = blockIdx.x;
    int b = bk / 900;
    int cam = threadIdx.x >> 6, j = threadIdx.x & 63;
    int cid = cam * 7200 + bk;

    float p0 = points[(size_t)bk * 3 + 0];
    float p1 = points[(size_t)bk * 3 + 1];
    float p2 = points[(size_t)bk * 3 + 2];
    const float* M = camM + cam * 6;
    float s0 = M[0] * p0 + M[1] * p1 + M[2] * p2 + camb[cam * 2 + 0];
    float s1 = M[3] * p0 + M[4] * p1 + M[5] * p2 + camb[cam * 2 + 1];
    float px0 = (1.f / (1.f + expf(-s0))) * 32.f;
    float px1 = (1.f / (1.f + expf(-s1))) * 88.f;
    float gx = 2.f * px0 / 32.f - 1.f, gy = 2.f * px1 / 88.f - 1.f;
    float ix = (gx + 1.f) * 0.5f * 87.f;
    float iy = (gy + 1.f) * 0.5f * 31.f;
    float x0 = floorf(ix), y0 = floorf(iy), x1 = x0 + 1.f, y1 = y0 + 1.f;
    float wx1 = ix - x0, wx0 = x1 - ix, wy1 = iy - y0, wy0 = y1 - iy;
    float m00 = (x0 >= 0.f && x0 <= 87.f && y0 >= 0.f && y0 <= 31.f) ? 1.f : 0.f;
    float m01 = (x1 >= 0.f && x1 <= 87.f && y0 >= 0.f && y0 <= 31.f) ? 1.f : 0.f;
    float m10 = (x0 >= 0.f && x0 <= 87.f && y1 >= 0.f && y1 <= 31.f) ? 1.f : 0.f;
    float m11 = (x1 >= 0.f && x1 <= 87.f && y1 >= 0.f && y1 <= 31.f) ? 1.f : 0.f;
    float w00 = wx0 * wy0 * m00, w01 = wx1 * wy0 * m01, w10 = wx0 * wy1 * m10, w11 = wx1 * wy1 * m11;
    int xi0 = (int)fminf(fmaxf(x0, 0.f), 87.f);
    int xi1 = (int)fminf(fmaxf(x1, 0.f), 87.f);
    int yi0 = (int)fminf(fmaxf(y0, 0.f), 31.f);
    int yi1 = (int)fminf(fmaxf(y1, 0.f), 31.f);

    size_t base = (size_t)(cam * 8 + b) * 2816;
    const float* f00 = Foff + (base + yi0 * 88 + xi0) * 64;
    const float* f01 = Foff + (base + yi0 * 88 + xi1) * 64;
    const float* f10 = Foff + (base + yi1 * 88 + xi0) * 64;
    const float* f11 = Foff + (base + yi1 * 88 + xi1) * 64;

    float o = qWoff[(size_t)bk * 64 + j]
            + w00 * f00[j] + w01 * f01[j] + w10 * f10[j] + w11 * f11[j];
    offs[(size_t)cid * 64 + j] = o;
    if (j == 0) { pxy[cid * 2 + 0] = px0; pxy[cid * 2 + 1] = px1; }
}

// ---------------- split-bf16 MFMA GEMM (fp32 A/B in): C = A@B^T + bias ----------------
template <bool SPLIT, bool C_BF16>
__global__ __launch_bounds__(256) void gemm_bf16(
    const float* __restrict__ A, long long aBatch,
    const float* __restrict__ B, const float* __restrict__ bias,
    void* __restrict__ Cv, long long cBatch,
    int M, int N, int K, int lda) {
    __shared__ __align__(16) unsigned short Ah[64][40];
    __shared__ __align__(16) unsigned short Bh[64][40];
    __shared__ __align__(16) unsigned short Al[(SPLIT ? 64 : 1)][40];
    __shared__ __align__(16) unsigned short Bl[(SPLIT ? 64 : 1)][40];

    const int tid = threadIdx.x;
    const int m0 = blockIdx.x * 64, n0 = blockIdx.y * 64;
    const int batch = blockIdx.z;
    const float* Ab = A + (size_t)batch * aBatch;
    const int lane = tid & 63, wave = tid >> 6;
    const int wr = wave & 1, wc = wave >> 1;
    const int lrow = lane & 15, lk = lane >> 4;

    f32x4 acc[2][2] = {};

    for (int kt = 0; kt < K; kt += 32) {
        if (kt) __syncthreads();
        {
            int c4 = (tid & 7) * 4;
#pragma unroll
            for (int rep = 0; rep < 2; rep++) {
                int r = (tid >> 3) + rep * 32;
                int m = m0 + r; if (m >= M) m = M - 1;
                f32x4 v = *(const f32x4*)(Ab + (size_t)m * lda + kt + c4);
#pragma unroll
                for (int q = 0; q < 4; q++) {
                    unsigned short h = f2bf(v[q]);
                    Ah[r][c4 + q] = h;
                    if (SPLIT) Al[r][c4 + q] = f2bf(v[q] - bf2f(h));
                }
            }
        }
        {
            int c4 = (tid & 7) * 4;
#pragma unroll
            for (int rep = 0; rep < 2; rep++) {
                int r = (tid >> 3) + rep * 32;
                f32x4 v = *(const f32x4*)(B + (size_t)(n0 + r) * K + kt + c4);
#pragma unroll
                for (int q = 0; q < 4; q++) {
                    unsigned short h = f2bf(v[q]);
                    Bh[r][c4 + q] = h;
                    if (SPLIT) Bl[r][c4 + q] = f2bf(v[q] - bf2f(h));
                }
            }
        }
        __syncthreads();

        bf16x8 a_h[2], b_h[2], a_l[2], b_l[2];
#pragma unroll
        for (int i = 0; i < 2; i++) {
            a_h[i] = *(const bf16x8*)&Ah[wr * 32 + i * 16 + lrow][lk * 8];
            b_h[i] = *(const bf16x8*)&Bh[wc * 32 + i * 16 + lrow][lk * 8];
            if (SPLIT) {
                a_l[i] = *(const bf16x8*)&Al[wr * 32 + i * 16 + lrow][lk * 8];
                b_l[i] = *(const bf16x8*)&Bl[wc * 32 + i * 16 + lrow][lk * 8];
            }
        }
#pragma unroll
        for (int i = 0; i < 2; i++)
#pragma unroll
            for (int j = 0; j < 2; j++) {
                acc[i][j] = __builtin_amdgcn_mfma_f32_16x16x32_bf16(a_h[i], b_h[j], acc[i][j], 0, 0, 0);
                if (SPLIT) {
                    acc[i][j] = __builtin_amdgcn_mfma_f32_16x16x32_bf16(a_h[i], b_l[j], acc[i][j], 0, 0, 0);
                    acc[i][j] = __builtin_amdgcn_mfma_f32_16x16x32_bf16(a_l[i], b_h[j], acc[i][j], 0, 0, 0);
                }
            }
    }

#pragma unroll
    for (int i = 0; i < 2; i++)
#pragma unroll
        for (int j = 0; j < 2; j++) {
            int n = n0 + wc * 32 + j * 16 + lrow;
            float bs = bias[n];
#pragma unroll
            for (int jj = 0; jj < 4; jj++) {
                int m = m0 + wr * 32 + i * 16 + lk * 4 + jj;
                if (m < M) {
                    float val = acc[i][j][jj] + bs;
                    if (C_BF16)
                        ((unsigned short*)Cv)[(size_t)batch * cBatch + (size_t)m * N + n] = f2bf(val);
                    else
                        ((float*)Cv)[(size_t)batch * cBatch + (size_t)m * N + n] = val;
                }
            }
        }
}

// ---------------- fused deformable attention (head-interleaved kv_t, x4 gathers) ----------------
__global__ __launch_bounds__(512) void attn_kernel(
    const float* __restrict__ q_proj, const float* __restrict__ pxy,
    const float* __restrict__ offs, const unsigned short* __restrict__ kv_t,
    float* __restrict__ S) {
    int bk = blockIdx.x;            // b*900 + k
    int b = bk / 900, k = bk % 900;
    int h = threadIdx.x >> 6;       // wave = head
    int lane = threadIdx.x & 63;

    __shared__ __align__(16) float        ldsW[8][24][4];
    __shared__ __align__(16) unsigned int ldsI[8][24][4];
    __shared__ float ldsL[8][24];

    if (lane < 24) {
        int cam = lane >> 2, p = lane & 3;
        int cid = cam * 7200 + bk;
        float px0 = pxy[cid * 2 + 0], px1 = pxy[cid * 2 + 1];
        float o0 = offs[(size_t)cid * 64 + (h * 4 + p) * 2 + 0];
        float o1 = offs[(size_t)cid * 64 + (h * 4 + p) * 2 + 1];
        float pc0 = px0 + o0 * (1.f / 32.f);
        float pc1 = px1 + o1 * (1.f / 88.f);
        float gx = 2.f * (pc0 * (1.f / 32.f)) - 1.f;
        float gy = 2.f * (pc1 * (1.f / 88.f)) - 1.f;
        float ix = (gx + 1.f) * 0.5f * 87.f;
        float iy = (gy + 1.f) * 0.5f * 31.f;
        float x0 = floorf(ix), y0 = floorf(iy), x1 = x0 + 1.f, y1 = y0 + 1.f;
        float wx1 = ix - x0, wx0 = x1 - ix, wy1 = iy - y0, wy0 = y1 - iy;
        float m00 = (x0 >= 0.f && x0 <= 87.f && y0 >= 0.f && y0 <= 31.f) ? 1.f : 0.f;
        float m01 = (x1 >= 0.f && x1 <= 87.f && y0 >= 0.f && y0 <= 31.f) ? 1.f : 0.f;
        float m10 = (x0 >= 0.f && x0 <= 87.f && y1 >= 0.f && y1 <= 31.f) ? 1.f : 0.f;
        float m11 = (x1 >= 0.f && x1 <= 87.f && y1 >= 0.f && y1 <= 31.f) ? 1.f : 0.f;
        int xi0 = (int)fminf(fmaxf(x0, 0.f), 87.f);
        int xi1 = (int)fminf(fmaxf(x1, 0.f), 87.f);
        int yi0 = (int)fminf(fmaxf(y0, 0.f), 31.f);
        int yi1 = (int)fminf(fmaxf(y1, 0.f), 31.f);
        unsigned int img = (unsigned int)(cam * 8 + b) * 2816u;
        ldsW[h][lane][0] = wx0 * wy0 * m00;
        ldsW[h][lane][1] = wx1 * wy0 * m01;
        ldsW[h][lane][2] = wx0 * wy1 * m10;
        ldsW[h][lane][3] = wx1 * wy1 * m11;
        ldsI[h][lane][0] = (img + yi0 * 88 + xi0) * 1024u;
        ldsI[h][lane][1] = (img + yi0 * 88 + xi1) * 1024u;
        ldsI[h][lane][2] = (img + yi1 * 88 + xi0) * 1024u;
        ldsI[h][lane][3] = (img + yi1 * 88 + xi1) * 1024u;
    }
    __syncthreads();

    const int p8 = lane >> 3, dlane = lane & 7;
    const int chB = h * 128 + dlane * 16;    // byte offset within pixel row
    const char* kvb = (const char*)kv_t;

    f32x4 qa = *(const f32x4*)(q_proj + (size_t)bk * 256 + h * 32 + (dlane & 3) * 8);
    f32x4 qb = *(const f32x4*)(q_proj + (size_t)bk * 256 + h * 32 + (dlane & 3) * 8 + 4);

    float vr[3][8];
    const float inv_sqrt = 0.17677669529663687f;
#pragma unroll
    for (int it = 0; it < 3; ++it) {
        int l = it * 8 + p8;
        f32x4 w = *(const f32x4*)ldsW[h][l];
        unsigned int i0 = ldsI[h][l][0], i1 = ldsI[h][l][1];
        unsigned int i2 = ldsI[h][l][2], i3 = ldsI[h][l][3];
        u32x4 u0 = *(const u32x4*)(kvb + i0 + chB);
        u32x4 u1 = *(const u32x4*)(kvb + i1 + chB);
        u32x4 u2 = *(const u32x4*)(kvb + i2 + chB);
        u32x4 u3 = *(const u32x4*)(kvb + i3 + chB);
#pragma unroll
        for (int q = 0; q < 4; ++q) {
            vr[it][2 * q] = w[0] * u2f(u0[q] << 16) + w[1] * u2f(u1[q] << 16)
                          + w[2] * u2f(u2[q] << 16) + w[3] * u2f(u3[q] << 16);
            vr[it][2 * q + 1] = w[0] * u2f(u0[q] & 0xFFFF0000u) + w[1] * u2f(u1[q] & 0xFFFF0000u)
                              + w[2] * u2f(u2[q] & 0xFFFF0000u) + w[3] * u2f(u3[q] & 0xFFFF0000u);
        }
        float t = qa[0] * vr[it][0] + qa[1] * vr[it][1] + qa[2] * vr[it][2] + qa[3] * vr[it][3]
                + qb[0] * vr[it][4] + qb[1] * vr[it][5] + qb[2] * vr[it][6] + qb[3] * vr[it][7];
        t += __shfl_xor(t, 1);
        t += __shfl_xor(t, 2);
        if (dlane == 0) ldsL[h][l] = t * inv_sqrt;
    }
    __syncthreads();

    float mx = -1e30f;
#pragma unroll
    for (int l = 0; l < 24; l++) mx = fmaxf(mx, ldsL[h][l]);
    float ssum = 0.f;
    float at3[3];
#pragma unroll
    for (int l = 0; l < 24; l++) {
        float e = __expf(ldsL[h][l] - mx);
        ssum += e;
        if ((l & 7) == p8) at3[l >> 3] = e;
    }
    float inv = 1.f / ssum;

    float o[8];
#pragma unroll
    for (int j = 0; j < 8; ++j)
        o[j] = at3[0] * vr[0][j] + at3[1] * vr[1][j] + at3[2] * vr[2][j];
#pragma unroll
    for (int j = 0; j < 8; ++j) {
        o[j] += __shfl_xor(o[j], 8);
        o[j] += __shfl_xor(o[j], 16);
        o[j] += __shfl_xor(o[j], 32);
    }
    if (p8 == 0 && dlane >= 4) {
        int d0 = (dlane - 4) * 8;
        f32x4 v0, v1;
        v0[0] = o[0] * inv; v0[1] = o[1] * inv; v0[2] = o[2] * inv; v0[3] = o[3] * inv;
        v1[0] = o[4] * inv; v1[1] = o[5] * inv; v1[2] = o[6] * inv; v1[3] = o[7] * inv;
        float* dst = &S[(size_t)b * 230400 + (size_t)h * 28800 + k * 32 + d0];
        *(f32x4*)dst = v0;
        *(f32x4*)(dst + 4) = v1;
    }
}

extern "C" void kernel_launch(void* const* d_in, const int* in_sizes, int n_in,
                              void* d_out, int out_size, void* d_ws, size_t ws_size,
                              hipStream_t stream) {
    const float* query    = (const float*)d_in[0];
    const float* points   = (const float*)d_in[1];
    const float* features = (const float*)d_in[2];
    const float* camM     = (const float*)d_in[3];
    const float* camb     = (const float*)d_in[4];
    const float* W_off    = (const float*)d_in[5];
    const float* b_off    = (const float*)d_in[6];
    const float* W_q      = (const float*)d_in[7];
    const float* b_q      = (const float*)d_in[8];
    const float* W_k      = (const float*)d_in[9];
    const float* b_k      = (const float*)d_in[10];
    const float* W_v      = (const float*)d_in[11];
    const float* b_v      = (const float*)d_in[12];
    const float* W_o      = (const float*)d_in[13];
    const float* b_o      = (const float*)d_in[14];

    char* ws = (char*)d_ws;
    unsigned short* feat_t = (unsigned short*)ws; ws += 69206016;   // blocked [1056][8][128][32] bf16
    unsigned short* kv_t   = (unsigned short*)ws; ws += 138412032;  // [135168][8 heads][64] bf16
    float* Foff   = (float*)ws; ws += 34603008;                     // [135168][64]
    float* offs   = (float*)ws; ws += 11059200;                     // [43200][64]
    float* pxy    = (float*)ws; ws += 345600;                       // [43200][2]
    float* qWoff  = (float*)ws; ws += 1843200;                      // [7200][64]
    float* q_proj = (float*)ws; ws += 7372800;                      // [7200][256]
    float* S      = (float*)ws; ws += 7372800;                      // [8][230400] scrambled
    unsigned short* Wkv = (unsigned short*)ws; ws += 524288;        // blocked [4][8][128][32] bf16
    float* bkv    = (float*)ws; ws += 2048;                         // [512]
    unsigned short* Woffp = (unsigned short*)ws; ws += 65536;       // blocked [8 kt][4096] bf16

    prep_wkv<<<512, 256, 0, stream>>>(W_k, b_k, W_v, b_v, Wkv, bkv);
    prep_woff<<<64, 256, 0, stream>>>(W_off, Woffp);
    transpose_feat<<<dim3(88, 8, 48), 256, 0, stream>>>(features, feat_t);
    // kv_t (bn 0-7, head-interleaved) + Foff (bn 8) : 256x64 tiles, barrier-free K-loop
    gemm_kv2<<<4752, 256, 0, stream>>>(feat_t, Wkv, Woffp, bkv, kv_t, Foff);
    // qWoff = query @ W_off^T + b_off : [7200 x 64]
    gemm_bf16<true, false><<<dim3(113, 1, 1), 256, 0, stream>>>(
        query, 0, W_off, b_off, qWoff, 0, 7200, 64, 256, 256);
    // offs[cid][64] = qWoff[bk] + bilinear(Foff); pxy
    sample_offs<<<7200, 384, 0, stream>>>(points, camM, camb, Foff, qWoff, offs, pxy);
    // q_proj = query @ W_q^T + b_q : [7200 x 256]
    gemm_bf16<true, false><<<dim3(113, 4, 1), 256, 0, stream>>>(
        query, 0, W_q, b_q, q_proj, 0, 7200, 256, 256, 256);
    attn_kernel<<<7200, 512, 0, stream>>>(q_proj, pxy, offs, kv_t, S);
    // out = S @ W_o^T + b_o : [7200 x 256]
    gemm_bf16<true, false><<<dim3(113, 4, 1), 256, 0, stream>>>(
        S, 0, W_o, b_o, d_out, 0, 7200, 256, 256, 256);
}

// Round 14
// 246.046 us; speedup vs baseline: 1.0556x; 1.0556x over previous
//
#include <hip/hip_runtime.h>

typedef __attribute__((ext_vector_type(4))) float f32x4;
typedef __attribute__((ext_vector_type(8))) short bf16x8;
typedef __attribute__((ext_vector_type(4))) unsigned int u32x4;

__device__ __forceinline__ unsigned short f2bf(float f) {
    union { float f; unsigned int u; } x; x.f = f;
    unsigned int u = x.u;
    return (unsigned short)((u + 0x7FFFu + ((u >> 16) & 1u)) >> 16);
}
__device__ __forceinline__ float bf2f(unsigned short b) {
    union { unsigned int u; float f; } x; x.u = ((unsigned int)b) << 16;
    return x.f;
}
__device__ __forceinline__ float u2f(unsigned int u) {
    union { unsigned int u; float f; } x; x.u = u; return x.f;
}

// blocked layout (row r, ch k), 128-row blocks: ((r>>7)*8 + (k>>5))*4096 + (r&127)*32 + (k&31)
// LDS tiles: 16B-chunk XOR swizzle, chunk c of row r at c ^ ((r>>1)&3); staging pre-swizzles
// the per-lane GLOBAL source (LDS dest linear); reads use chunk lk ^ ((lrow>>1)&3).
// kv_t layout: [pixel][head][K ch 0-31 | V ch 0-31] bf16 (head-interleaved, 128B per head).

// ---------------- prep (merged): Wkv blocked bf16, Woff blocked bf16, Wcat=[Wq|Woff] fp32 ----------------
__global__ void prep_all(const float* __restrict__ Wk, const float* __restrict__ bk,
                         const float* __restrict__ Wv, const float* __restrict__ bv,
                         const float* __restrict__ Wq, const float* __restrict__ bq,
                         const float* __restrict__ Woff, const float* __restrict__ boff,
                         unsigned short* __restrict__ Wkv, float* __restrict__ bkv,
                         unsigned short* __restrict__ Woffp,
                         float* __restrict__ Wcat, float* __restrict__ bcat) {
    int i = blockIdx.x * 256 + threadIdx.x;   // grid 512*256 = 131072
    if (i < 512 * 256) {
        int n = i >> 8, k = i & 255;
        float v = (n < 256) ? Wk[i] : Wv[i - 65536];
        Wkv[((size_t)(n >> 7) * 8 + (k >> 5)) * 4096 + (n & 127) * 32 + (k & 31)] = f2bf(v);
    }
    if (i < 512) bkv[i] = (i < 256) ? bk[i] : bv[i - 256];
    if (i < 64 * 256) {
        int n = i >> 8, k = i & 255;
        Woffp[(size_t)(k >> 5) * 4096 + n * 32 + (k & 31)] = f2bf(Woff[i]);
    }
    if (i < 320 * 256) Wcat[i] = (i < 65536) ? Wq[i] : Woff[i - 65536];
    if (i < 320) bcat[i] = (i < 256) ? bq[i] : boff[i - 256];
}

// ---------------- transpose features [48][256][2816] -> bf16 blocked ----------------
__global__ __launch_bounds__(256) void transpose_feat(const float* __restrict__ src,
                                                      unsigned short* __restrict__ dst) {
    __shared__ float tile[32][33];
    int img = blockIdx.z;
    int p0 = blockIdx.x * 32;   // pixel
    int d0 = blockIdx.y * 32;   // channel
    int tx = threadIdx.x & 31, ty = threadIdx.x >> 5;
    const float* s = src + (size_t)img * 256 * 2816;
#pragma unroll
    for (int i = 0; i < 4; i++) tile[ty + 8 * i][tx] = s[(size_t)(d0 + ty + 8 * i) * 2816 + p0 + tx];
    __syncthreads();
    int m = img * 2816 + p0;
    unsigned short* o = dst + ((size_t)(m >> 7) * 8 + (d0 >> 5)) * 4096 + (m & 127) * 32;
#pragma unroll
    for (int i = 0; i < 4; i++) o[(ty + 8 * i) * 32 + tx] = f2bf(tile[tx][ty + 8 * i]);
}

// ---------------- kv+off projection: barrier-free counted-vmcnt pipeline, 64KB LDS ----------------
// bn 0..7: kv_t (head-interleaved cols) = A @ Wkv^T + bkv (64 original cols per bn)
// bn 8   : Foff[135168][64] fp32 = A @ Woff^T (no bias)
// Block = 128 px x 64 cols; 4 waves, wave w owns rows 32w..32w+31 (wave-private A staging,
// NO barriers and NO lgkm drains in the K-loop). B (64x256, 32KB) staged once.
// A ring: 4 slots x 8KB, depth-3 prefetch, per-wave counted s_waitcnt vmcnt(N).
__global__ __launch_bounds__(256, 2) void gemm_kv2(
    const unsigned short* __restrict__ A,
    const unsigned short* __restrict__ Wkv,
    const unsigned short* __restrict__ Woffp,
    const float* __restrict__ bias,
    unsigned short* __restrict__ C,
    float* __restrict__ Foff) {
    __shared__ __align__(16) unsigned short Bl[16384];    // 32KB: [kt][64r][32c] (swizzled)
    __shared__ __align__(16) unsigned short Ar[4][4096];  // ring: [slot][128r][32c] (swizzled)

    const int tid = threadIdx.x, lane = tid & 63, w = tid >> 6;
    const int lrow = lane & 15, lk = lane >> 4;
    const int lsw = (lane >> 2) * 32 + (((lane & 3) ^ ((lane >> 3) & 3)) * 8);
    const int ckx = ((lrow >> 1) & 3);    // read-side chunk xor
    const int bid = blockIdx.x;
    const int wgid = (bid & 7) * 1188 + (bid >> 3);  // XCD swizzle (9504 = 8*1188)
    const int chunk = wgid / 9, bn = wgid % 9;       // chunk: m-block 0..1055, bn: 0..8

    const unsigned short* A0 = A + (size_t)chunk * 32768;
    const unsigned short* Bb = (bn < 8)
        ? Wkv + (size_t)(bn >> 1) * 32768 + (bn & 1) * 2048
        : Woffp;
    const int wof = w * 1024;   // wave-private 32-row region (shorts) within a slot

    // stage B fully (32KB): wave w stages kt = 2w, 2w+1 (8 x 1KB, pre-swizzled source)
#pragma unroll
    for (int i = 0; i < 8; ++i) {
        int kt = w * 2 + (i >> 2), part = i & 3;
        __builtin_amdgcn_global_load_lds(
            (const __attribute__((address_space(1))) unsigned int*)(Bb + kt * 4096 + part * 512 + lsw),
            (__attribute__((address_space(3))) unsigned int*)&Bl[kt * 2048 + part * 512], 16, 0, 0);
    }

#define STAGE_STEP(S)                                                                        \
    {                                                                                        \
        __builtin_amdgcn_global_load_lds(                                                    \
            (const __attribute__((address_space(1))) unsigned int*)(A0 + (S) * 4096 + wof + lsw),        \
            (__attribute__((address_space(3))) unsigned int*)&Ar[(S) & 3][wof], 16, 0, 0);   \
        __builtin_amdgcn_global_load_lds(                                                    \
            (const __attribute__((address_space(1))) unsigned int*)(A0 + (S) * 4096 + wof + 512 + lsw),  \
            (__attribute__((address_space(3))) unsigned int*)&Ar[(S) & 3][wof + 512], 16, 0, 0);         \
    }

    STAGE_STEP(0) STAGE_STEP(1) STAGE_STEP(2)
    __syncthreads();   // drains vmcnt(0): B + A0..A2 resident

    f32x4 acc[2][4] = {};   // [i][j]

    // COMP: wait A(S) landed (counted) -> ds_read frags -> stage A(S+3) (no lgkm drain:
    // slot (S+3)&3 = (S-1)&3 was consumed by step S-1's MFMAs) -> MFMAs.
#define COMP_STEP(S, NW)                                                                     \
    {                                                                                        \
        asm volatile("s_waitcnt vmcnt(%0)" :: "i"(NW) : "memory");                           \
        bf16x8 bfr[4], af[2];                                                                \
        _Pragma("unroll") for (int j = 0; j < 4; ++j)                                        \
            bfr[j] = *(const bf16x8*)&Bl[(S) * 2048 + (j * 16 + lrow) * 32 + (lk ^ ckx) * 8];\
        _Pragma("unroll") for (int i = 0; i < 2; ++i)                                        \
            af[i] = *(const bf16x8*)&Ar[(S) & 3][wof + i * 512 + lrow * 32 + (lk ^ ckx) * 8];\
        if ((S) + 3 < 8) STAGE_STEP((S) + 3)                                                 \
        _Pragma("unroll") for (int i = 0; i < 2; ++i)                                        \
            _Pragma("unroll") for (int j = 0; j < 4; ++j)                                    \
                acc[i][j] = __builtin_amdgcn_mfma_f32_16x16x32_bf16(af[i], bfr[j], acc[i][j], 0, 0, 0); \
    }

    // outstanding-loads audit (per wave, 2 loads/stage; prologue drained by barrier):
    // s0:+A3(2) s1:+A4(4) s2:+A5(6) s3 needs A3->vmcnt(4),+A6(6) s4 needs A4->vmcnt(4),+A7(6)
    // s5 needs A5->vmcnt(4)(4 left) s6 needs A6->vmcnt(2) s7 needs A7->vmcnt(0)
    COMP_STEP(0, 63) COMP_STEP(1, 63) COMP_STEP(2, 63) COMP_STEP(3, 4)
    COMP_STEP(4, 4)  COMP_STEP(5, 4)  COMP_STEP(6, 2)  COMP_STEP(7, 0)
#undef COMP_STEP
#undef STAGE_STEP

    if (bn < 8) {
        // epilogue: acc -> LDS [128][64] bf16 -> coalesced 16B stores, head-interleaved cols
        unsigned short* Cl = &Ar[0][0];   // 16KB of the 32KB ring
        __syncthreads();
#pragma unroll
        for (int j = 0; j < 4; ++j) {
            float bs = bias[bn * 64 + j * 16 + lrow];
#pragma unroll
            for (int i = 0; i < 2; ++i)
#pragma unroll
                for (int jj = 0; jj < 4; ++jj)
                    Cl[(w * 32 + i * 16 + lk * 4 + jj) * 64 + j * 16 + lrow] =
                        f2bf(acc[i][j][jj] + bs);
        }
        __syncthreads();
        // original col g = bn*64 + col8*8; K (bn<4): dst h*64+d; V (bn>=4): dst h*64+32+d
#pragma unroll
        for (int it = 0; it < 4; ++it) {
            int idx = it * 256 + tid;
            int row = idx >> 3, col8 = idx & 7;
            int dstcol = (bn < 4)
                ? (bn * 2 + (col8 >> 2)) * 64 + (col8 & 3) * 8
                : ((bn - 4) * 2 + (col8 >> 2)) * 64 + 32 + (col8 & 3) * 8;
            *(f32x4*)(C + (size_t)(chunk * 128 + row) * 512 + dstcol) =
                *(const f32x4*)&Cl[row * 64 + col8 * 8];
        }
    } else {
        // Foff epilogue: fp32 direct stores (no bias)
#pragma unroll
        for (int i = 0; i < 2; ++i)
#pragma unroll
            for (int j = 0; j < 4; ++j)
#pragma unroll
                for (int jj = 0; jj < 4; ++jj) {
                    int m = chunk * 128 + w * 32 + i * 16 + lk * 4 + jj;
                    Foff[(size_t)m * 64 + j * 16 + lrow] = acc[i][j][jj];
                }
    }
}

// ---------------- sample_offs: project points, bilinear-blend Foff, add qcat[:,256:320] ----------------
__global__ __launch_bounds__(384) void sample_offs(
    const float* __restrict__ points, const float* __restrict__ camM,
    const float* __restrict__ camb, const float* __restrict__ Foff,
    const float* __restrict__ qcat,
    float* __restrict__ offs, float* __restrict__ pxy) {
    int bk = blockIdx.x;
    int b = bk / 900;
    int cam = threadIdx.x >> 6, j = threadIdx.x & 63;
    int cid = cam * 7200 + bk;

    float p0 = points[(size_t)bk * 3 + 0];
    float p1 = points[(size_t)bk * 3 + 1];
    float p2 = points[(size_t)bk * 3 + 2];
    const float* M = camM + cam * 6;
    float s0 = M[0] * p0 + M[1] * p1 + M[2] * p2 + camb[cam * 2 + 0];
    float s1 = M[3] * p0 + M[4] * p1 + M[5] * p2 + camb[cam * 2 + 1];
    float px0 = (1.f / (1.f + expf(-s0))) * 32.f;
    float px1 = (1.f / (1.f + expf(-s1))) * 88.f;
    float gx = 2.f * px0 / 32.f - 1.f, gy = 2.f * px1 / 88.f - 1.f;
    float ix = (gx + 1.f) * 0.5f * 87.f;
    float iy = (gy + 1.f) * 0.5f * 31.f;
    float x0 = floorf(ix), y0 = floorf(iy), x1 = x0 + 1.f, y1 = y0 + 1.f;
    float wx1 = ix - x0, wx0 = x1 - ix, wy1 = iy - y0, wy0 = y1 - iy;
    float m00 = (x0 >= 0.f && x0 <= 87.f && y0 >= 0.f && y0 <= 31.f) ? 1.f : 0.f;
    float m01 = (x1 >= 0.f && x1 <= 87.f && y0 >= 0.f && y0 <= 31.f) ? 1.f : 0.f;
    float m10 = (x0 >= 0.f && x0 <= 87.f && y1 >= 0.f && y1 <= 31.f) ? 1.f : 0.f;
    float m11 = (x1 >= 0.f && x1 <= 87.f && y1 >= 0.f && y1 <= 31.f) ? 1.f : 0.f;
    float w00 = wx0 * wy0 * m00, w01 = wx1 * wy0 * m01, w10 = wx0 * wy1 * m10, w11 = wx1 * wy1 * m11;
    int xi0 = (int)fminf(fmaxf(x0, 0.f), 87.f);
    int xi1 = (int)fminf(fmaxf(x1, 0.f), 87.f);
    int yi0 = (int)fminf(fmaxf(y0, 0.f), 31.f);
    int yi1 = (int)fminf(fmaxf(y1, 0.f), 31.f);

    size_t base = (size_t)(cam * 8 + b) * 2816;
    const float* f00 = Foff + (base + yi0 * 88 + xi0) * 64;
    const float* f01 = Foff + (base + yi0 * 88 + xi1) * 64;
    const float* f10 = Foff + (base + yi1 * 88 + xi0) * 64;
    const float* f11 = Foff + (base + yi1 * 88 + xi1) * 64;

    float o = qcat[(size_t)bk * 320 + 256 + j]
            + w00 * f00[j] + w01 * f01[j] + w10 * f10[j] + w11 * f11[j];
    offs[(size_t)cid * 64 + j] = o;
    if (j == 0) { pxy[cid * 2 + 0] = px0; pxy[cid * 2 + 1] = px1; }
}

// ---------------- split-bf16 MFMA GEMM (fp32 A/B in): C = A@B^T + bias ----------------
template <bool SPLIT, bool C_BF16>
__global__ __launch_bounds__(256) void gemm_bf16(
    const float* __restrict__ A, long long aBatch,
    const float* __restrict__ B, const float* __restrict__ bias,
    void* __restrict__ Cv, long long cBatch,
    int M, int N, int K, int lda) {
    __shared__ __align__(16) unsigned short Ah[64][40];
    __shared__ __align__(16) unsigned short Bh[64][40];
    __shared__ __align__(16) unsigned short Al[(SPLIT ? 64 : 1)][40];
    __shared__ __align__(16) unsigned short Bl[(SPLIT ? 64 : 1)][40];

    const int tid = threadIdx.x;
    const int m0 = blockIdx.x * 64, n0 = blockIdx.y * 64;
    const int batch = blockIdx.z;
    const float* Ab = A + (size_t)batch * aBatch;
    const int lane = tid & 63, wave = tid >> 6;
    const int wr = wave & 1, wc = wave >> 1;
    const int lrow = lane & 15, lk = lane >> 4;

    f32x4 acc[2][2] = {};

    for (int kt = 0; kt < K; kt += 32) {
        if (kt) __syncthreads();
        {
            int c4 = (tid & 7) * 4;
#pragma unroll
            for (int rep = 0; rep < 2; rep++) {
                int r = (tid >> 3) + rep * 32;
                int m = m0 + r; if (m >= M) m = M - 1;
                f32x4 v = *(const f32x4*)(Ab + (size_t)m * lda + kt + c4);
#pragma unroll
                for (int q = 0; q < 4; q++) {
                    unsigned short h = f2bf(v[q]);
                    Ah[r][c4 + q] = h;
                    if (SPLIT) Al[r][c4 + q] = f2bf(v[q] - bf2f(h));
                }
            }
        }
        {
            int c4 = (tid & 7) * 4;
#pragma unroll
            for (int rep = 0; rep < 2; rep++) {
                int r = (tid >> 3) + rep * 32;
                f32x4 v = *(const f32x4*)(B + (size_t)(n0 + r) * K + kt + c4);
#pragma unroll
                for (int q = 0; q < 4; q++) {
                    unsigned short h = f2bf(v[q]);
                    Bh[r][c4 + q] = h;
                    if (SPLIT) Bl[r][c4 + q] = f2bf(v[q] - bf2f(h));
                }
            }
        }
        __syncthreads();

        bf16x8 a_h[2], b_h[2], a_l[2], b_l[2];
#pragma unroll
        for (int i = 0; i < 2; i++) {
            a_h[i] = *(const bf16x8*)&Ah[wr * 32 + i * 16 + lrow][lk * 8];
            b_h[i] = *(const bf16x8*)&Bh[wc * 32 + i * 16 + lrow][lk * 8];
            if (SPLIT) {
                a_l[i] = *(const bf16x8*)&Al[wr * 32 + i * 16 + lrow][lk * 8];
                b_l[i] = *(const bf16x8*)&Bl[wc * 32 + i * 16 + lrow][lk * 8];
            }
        }
#pragma unroll
        for (int i = 0; i < 2; i++)
#pragma unroll
            for (int j = 0; j < 2; j++) {
                acc[i][j] = __builtin_amdgcn_mfma_f32_16x16x32_bf16(a_h[i], b_h[j], acc[i][j], 0, 0, 0);
                if (SPLIT) {
                    acc[i][j] = __builtin_amdgcn_mfma_f32_16x16x32_bf16(a_h[i], b_l[j], acc[i][j], 0, 0, 0);
                    acc[i][j] = __builtin_amdgcn_mfma_f32_16x16x32_bf16(a_l[i], b_h[j], acc[i][j], 0, 0, 0);
                }
            }
    }

#pragma unroll
    for (int i = 0; i < 2; i++)
#pragma unroll
        for (int j = 0; j < 2; j++) {
            int n = n0 + wc * 32 + j * 16 + lrow;
            float bs = bias[n];
#pragma unroll
            for (int jj = 0; jj < 4; jj++) {
                int m = m0 + wr * 32 + i * 16 + lk * 4 + jj;
                if (m < M) {
                    float val = acc[i][j][jj] + bs;
                    if (C_BF16)
                        ((unsigned short*)Cv)[(size_t)batch * cBatch + (size_t)m * N + n] = f2bf(val);
                    else
                        ((float*)Cv)[(size_t)batch * cBatch + (size_t)m * N + n] = val;
                }
            }
        }
}

// ---------------- fused deformable attention (head-interleaved kv_t, x4 gathers) ----------------
__global__ __launch_bounds__(512) void attn_kernel(
    const float* __restrict__ qcat, const float* __restrict__ pxy,
    const float* __restrict__ offs, const unsigned short* __restrict__ kv_t,
    float* __restrict__ S) {
    int bk = blockIdx.x;            // b*900 + k
    int b = bk / 900, k = bk % 900;
    int h = threadIdx.x >> 6;       // wave = head
    int lane = threadIdx.x & 63;

    __shared__ __align__(16) float        ldsW[8][24][4];
    __shared__ __align__(16) unsigned int ldsI[8][24][4];
    __shared__ float ldsL[8][24];

    if (lane < 24) {
        int cam = lane >> 2, p = lane & 3;
        int cid = cam * 7200 + bk;
        float px0 = pxy[cid * 2 + 0], px1 = pxy[cid * 2 + 1];
        float o0 = offs[(size_t)cid * 64 + (h * 4 + p) * 2 + 0];
        float o1 = offs[(size_t)cid * 64 + (h * 4 + p) * 2 + 1];
        float pc0 = px0 + o0 * (1.f / 32.f);
        float pc1 = px1 + o1 * (1.f / 88.f);
        float gx = 2.f * (pc0 * (1.f / 32.f)) - 1.f;
        float gy = 2.f * (pc1 * (1.f / 88.f)) - 1.f;
        float ix = (gx + 1.f) * 0.5f * 87.f;
        float iy = (gy + 1.f) * 0.5f * 31.f;
        float x0 = floorf(ix), y0 = floorf(iy), x1 = x0 + 1.f, y1 = y0 + 1.f;
        float wx1 = ix - x0, wx0 = x1 - ix, wy1 = iy - y0, wy0 = y1 - iy;
        float m00 = (x0 >= 0.f && x0 <= 87.f && y0 >= 0.f && y0 <= 31.f) ? 1.f : 0.f;
        float m01 = (x1 >= 0.f && x1 <= 87.f && y0 >= 0.f && y0 <= 31.f) ? 1.f : 0.f;
        float m10 = (x0 >= 0.f && x0 <= 87.f && y1 >= 0.f && y1 <= 31.f) ? 1.f : 0.f;
        float m11 = (x1 >= 0.f && x1 <= 87.f && y1 >= 0.f && y1 <= 31.f) ? 1.f : 0.f;
        int xi0 = (int)fminf(fmaxf(x0, 0.f), 87.f);
        int xi1 = (int)fminf(fmaxf(x1, 0.f), 87.f);
        int yi0 = (int)fminf(fmaxf(y0, 0.f), 31.f);
        int yi1 = (int)fminf(fmaxf(y1, 0.f), 31.f);
        unsigned int img = (unsigned int)(cam * 8 + b) * 2816u;
        ldsW[h][lane][0] = wx0 * wy0 * m00;
        ldsW[h][lane][1] = wx1 * wy0 * m01;
        ldsW[h][lane][2] = wx0 * wy1 * m10;
        ldsW[h][lane][3] = wx1 * wy1 * m11;
        ldsI[h][lane][0] = (img + yi0 * 88 + xi0) * 1024u;
        ldsI[h][lane][1] = (img + yi0 * 88 + xi1) * 1024u;
        ldsI[h][lane][2] = (img + yi1 * 88 + xi0) * 1024u;
        ldsI[h][lane][3] = (img + yi1 * 88 + xi1) * 1024u;
    }
    __syncthreads();

    const int p8 = lane >> 3, dlane = lane & 7;
    const int chB = h * 128 + dlane * 16;    // byte offset within pixel row
    const char* kvb = (const char*)kv_t;

    f32x4 qa = *(const f32x4*)(qcat + (size_t)bk * 320 + h * 32 + (dlane & 3) * 8);
    f32x4 qb = *(const f32x4*)(qcat + (size_t)bk * 320 + h * 32 + (dlane & 3) * 8 + 4);

    float vr[3][8];
    const float inv_sqrt = 0.17677669529663687f;
#pragma unroll
    for (int it = 0; it < 3; ++it) {
        int l = it * 8 + p8;
        f32x4 w = *(const f32x4*)ldsW[h][l];
        unsigned int i0 = ldsI[h][l][0], i1 = ldsI[h][l][1];
        unsigned int i2 = ldsI[h][l][2], i3 = ldsI[h][l][3];
        u32x4 u0 = *(const u32x4*)(kvb + i0 + chB);
        u32x4 u1 = *(const u32x4*)(kvb + i1 + chB);
        u32x4 u2 = *(const u32x4*)(kvb + i2 + chB);
        u32x4 u3 = *(const u32x4*)(kvb + i3 + chB);
#pragma unroll
        for (int q = 0; q < 4; ++q) {
            vr[it][2 * q] = w[0] * u2f(u0[q] << 16) + w[1] * u2f(u1[q] << 16)
                          + w[2] * u2f(u2[q] << 16) + w[3] * u2f(u3[q] << 16);
            vr[it][2 * q + 1] = w[0] * u2f(u0[q] & 0xFFFF0000u) + w[1] * u2f(u1[q] & 0xFFFF0000u)
                              + w[2] * u2f(u2[q] & 0xFFFF0000u) + w[3] * u2f(u3[q] & 0xFFFF0000u);
        }
        float t = qa[0] * vr[it][0] + qa[1] * vr[it][1] + qa[2] * vr[it][2] + qa[3] * vr[it][3]
                + qb[0] * vr[it][4] + qb[1] * vr[it][5] + qb[2] * vr[it][6] + qb[3] * vr[it][7];
        t += __shfl_xor(t, 1);
        t += __shfl_xor(t, 2);
        if (dlane == 0) ldsL[h][l] = t * inv_sqrt;
    }
    __syncthreads();

    float mx = -1e30f;
#pragma unroll
    for (int l = 0; l < 24; l++) mx = fmaxf(mx, ldsL[h][l]);
    float ssum = 0.f;
    float at3[3];
#pragma unroll
    for (int l = 0; l < 24; l++) {
        float e = __expf(ldsL[h][l] - mx);
        ssum += e;
        if ((l & 7) == p8) at3[l >> 3] = e;
    }
    float inv = 1.f / ssum;

    float o[8];
#pragma unroll
    for (int j = 0; j < 8; ++j)
        o[j] = at3[0] * vr[0][j] + at3[1] * vr[1][j] + at3[2] * vr[2][j];
#pragma unroll
    for (int j = 0; j < 8; ++j) {
        o[j] += __shfl_xor(o[j], 8);
        o[j] += __shfl_xor(o[j], 16);
        o[j] += __shfl_xor(o[j], 32);
    }
    if (p8 == 0 && dlane >= 4) {
        int d0 = (dlane - 4) * 8;
        f32x4 v0, v1;
        v0[0] = o[0] * inv; v0[1] = o[1] * inv; v0[2] = o[2] * inv; v0[3] = o[3] * inv;
        v1[0] = o[4] * inv; v1[1] = o[5] * inv; v1[2] = o[6] * inv; v1[3] = o[7] * inv;
        float* dst = &S[(size_t)b * 230400 + (size_t)h * 28800 + k * 32 + d0];
        *(f32x4*)dst = v0;
        *(f32x4*)(dst + 4) = v1;
    }
}

extern "C" void kernel_launch(void* const* d_in, const int* in_sizes, int n_in,
                              void* d_out, int out_size, void* d_ws, size_t ws_size,
                              hipStream_t stream) {
    const float* query    = (const float*)d_in[0];
    const float* points   = (const float*)d_in[1];
    const float* features = (const float*)d_in[2];
    const float* camM     = (const float*)d_in[3];
    const float* camb     = (const float*)d_in[4];
    const float* W_off    = (const float*)d_in[5];
    const float* b_off    = (const float*)d_in[6];
    const float* W_q      = (const float*)d_in[7];
    const float* b_q      = (const float*)d_in[8];
    const float* W_k      = (const float*)d_in[9];
    const float* b_k      = (const float*)d_in[10];
    const float* W_v      = (const float*)d_in[11];
    const float* b_v      = (const float*)d_in[12];
    const float* W_o      = (const float*)d_in[13];
    const float* b_o      = (const float*)d_in[14];

    char* ws = (char*)d_ws;
    unsigned short* feat_t = (unsigned short*)ws; ws += 69206016;   // blocked [1056][8][128][32] bf16
    unsigned short* kv_t   = (unsigned short*)ws; ws += 138412032;  // [135168][8 heads][64] bf16
    float* Foff   = (float*)ws; ws += 34603008;                     // [135168][64]
    float* offs   = (float*)ws; ws += 11059200;                     // [43200][64]
    float* pxy    = (float*)ws; ws += 345600;                       // [43200][2]
    float* qcat   = (float*)ws; ws += 9216000;                      // [7200][320] = [q_proj | qWoff]
    float* S      = (float*)ws; ws += 7372800;                      // [8][230400] scrambled
    unsigned short* Wkv = (unsigned short*)ws; ws += 524288;        // blocked [4][8][128][32] bf16
    float* bkv    = (float*)ws; ws += 2048;                         // [512]
    unsigned short* Woffp = (unsigned short*)ws; ws += 65536;       // blocked [8 kt][4096] bf16
    float* Wcat   = (float*)ws; ws += 327680;                       // [320][256] fp32
    float* bcat   = (float*)ws; ws += 1280;                         // [320]

    prep_all<<<512, 256, 0, stream>>>(W_k, b_k, W_v, b_v, W_q, b_q, W_off, b_off,
                                      Wkv, bkv, Woffp, Wcat, bcat);
    transpose_feat<<<dim3(88, 8, 48), 256, 0, stream>>>(features, feat_t);
    // kv_t (bn 0-7, head-interleaved) + Foff (bn 8) : barrier-free counted-vmcnt pipeline
    gemm_kv2<<<9504, 256, 0, stream>>>(feat_t, Wkv, Woffp, bkv, kv_t, Foff);
    // qcat = query @ [W_q|W_off]^T + [b_q|b_off] : [7200 x 320]
    gemm_bf16<true, false><<<dim3(113, 5, 1), 256, 0, stream>>>(
        query, 0, Wcat, bcat, qcat, 0, 7200, 320, 256, 256);
    // offs[cid][64] = qcat[:,256:] + bilinear(Foff); pxy
    sample_offs<<<7200, 384, 0, stream>>>(points, camM, camb, Foff, qcat, offs, pxy);
    attn_kernel<<<7200, 512, 0, stream>>>(qcat, pxy, offs, kv_t, S);
    // out = S @ W_o^T + b_o : [7200 x 256]
    gemm_bf16<true, false><<<dim3(113, 4, 1), 256, 0, stream>>>(
        S, 0, W_o, b_o, d_out, 0, 7200, 256, 256, 256);
}

// Round 15
// 237.386 us; speedup vs baseline: 1.0941x; 1.0365x over previous
//
#include <hip/hip_runtime.h>

typedef __attribute__((ext_vector_type(4))) float f32x4;
typedef __attribute__((ext_vector_type(8))) short bf16x8;
typedef __attribute__((ext_vector_type(4))) unsigned int u32x4;

__device__ __forceinline__ unsigned short f2bf(float f) {
    union { float f; unsigned int u; } x; x.f = f;
    unsigned int u = x.u;
    return (unsigned short)((u + 0x7FFFu + ((u >> 16) & 1u)) >> 16);
}
__device__ __forceinline__ float bf2f(unsigned short b) {
    union { unsigned int u; float f; } x; x.u = ((unsigned int)b) << 16;
    return x.f;
}
__device__ __forceinline__ float u2f(unsigned int u) {
    union { unsigned int u; float f; } x; x.u = u; return x.f;
}

// blocked layout (row r, ch k), 128-row blocks: ((r>>7)*8 + (k>>5))*4096 + (r&127)*32 + (k&31)
// LDS tiles: 16B-chunk XOR swizzle, chunk c of row r at c ^ ((r>>1)&3); staging pre-swizzles
// the per-lane GLOBAL source (LDS dest linear); reads use chunk lk ^ ((lrow>>1)&3).
// kv_t layout: [pixel][head][K ch 0-31 | V ch 0-31] bf16 (head-interleaved, 128B per head).

// ---------------- prep (merged): Wkv blocked bf16, Woff blocked bf16, Wcat=[Wq|Woff] fp32 ----------------
__global__ void prep_all(const float* __restrict__ Wk, const float* __restrict__ bk,
                         const float* __restrict__ Wv, const float* __restrict__ bv,
                         const float* __restrict__ Wq, const float* __restrict__ bq,
                         const float* __restrict__ Woff, const float* __restrict__ boff,
                         unsigned short* __restrict__ Wkv, float* __restrict__ bkv,
                         unsigned short* __restrict__ Woffp,
                         float* __restrict__ Wcat, float* __restrict__ bcat) {
    int i = blockIdx.x * 256 + threadIdx.x;   // grid 512*256 = 131072
    if (i < 512 * 256) {
        int n = i >> 8, k = i & 255;
        float v = (n < 256) ? Wk[i] : Wv[i - 65536];
        Wkv[((size_t)(n >> 7) * 8 + (k >> 5)) * 4096 + (n & 127) * 32 + (k & 31)] = f2bf(v);
    }
    if (i < 512) bkv[i] = (i < 256) ? bk[i] : bv[i - 256];
    if (i < 64 * 256) {
        int n = i >> 8, k = i & 255;
        Woffp[(size_t)(k >> 5) * 4096 + n * 32 + (k & 31)] = f2bf(Woff[i]);
    }
    if (i < 320 * 256) Wcat[i] = (i < 65536) ? Wq[i] : Woff[i - 65536];
    if (i < 320) bcat[i] = (i < 256) ? bq[i] : boff[i - 256];
}

// ---------------- transpose features [48][256][2816] -> bf16 blocked ----------------
__global__ __launch_bounds__(256) void transpose_feat(const float* __restrict__ src,
                                                      unsigned short* __restrict__ dst) {
    __shared__ float tile[32][33];
    int img = blockIdx.z;
    int p0 = blockIdx.x * 32;   // pixel
    int d0 = blockIdx.y * 32;   // channel
    int tx = threadIdx.x & 31, ty = threadIdx.x >> 5;
    const float* s = src + (size_t)img * 256 * 2816;
#pragma unroll
    for (int i = 0; i < 4; i++) tile[ty + 8 * i][tx] = s[(size_t)(d0 + ty + 8 * i) * 2816 + p0 + tx];
    __syncthreads();
    int m = img * 2816 + p0;
    unsigned short* o = dst + ((size_t)(m >> 7) * 8 + (d0 >> 5)) * 4096 + (m & 127) * 32;
#pragma unroll
    for (int i = 0; i < 4; i++) o[(ty + 8 * i) * 32 + tx] = f2bf(tile[tx][ty + 8 * i]);
}

// ---------------- kv+off projection: counted-vmcnt pipelined GEMM, 40KB LDS (4 blocks/CU) ----------------
// bn 0..7: kv_t (head-interleaved cols) = A @ Wkv^T + bkv (64 original cols per bn)
// bn 8   : Foff[135168][64] fp32 = A @ Woff^T (no bias)
// Block = 128 px x 64 cols; 4 waves, wave-private A staging (no K-loop barriers except
// the half-B re-stage). B half (16KB, kt0-3) staged, re-staged mid-loop for kt4-7.
// A ring: 3 slots x 8KB, depth-2 prefetch, per-wave s_waitcnt vmcnt(N).
__global__ __launch_bounds__(256) void gemm_kv2(
    const unsigned short* __restrict__ A,
    const unsigned short* __restrict__ Wkv,
    const unsigned short* __restrict__ Woffp,
    const float* __restrict__ bias,
    unsigned short* __restrict__ C,
    float* __restrict__ Foff) {
    __shared__ __align__(16) unsigned short Bl[8192];     // 16KB: [kt&3][64r][32c] (swizzled)
    __shared__ __align__(16) unsigned short Ar[3][4096];  // ring: [slot][128r][32c] (swizzled)

    const int tid = threadIdx.x, lane = tid & 63, w = tid >> 6;
    const int lrow = lane & 15, lk = lane >> 4;
    const int lsw = (lane >> 2) * 32 + (((lane & 3) ^ ((lane >> 3) & 3)) * 8);
    const int ckx = ((lrow >> 1) & 3);    // read-side chunk xor
    const int bid = blockIdx.x;
    const int wgid = (bid & 7) * 1188 + (bid >> 3);  // XCD swizzle (9504 = 8*1188)
    const int chunk = wgid / 9, bn = wgid % 9;       // chunk: m-block 0..1055, bn: 0..8

    const unsigned short* A0 = A + (size_t)chunk * 32768;
    const unsigned short* Bb = (bn < 8)
        ? Wkv + (size_t)(bn >> 1) * 32768 + (bn & 1) * 2048
        : Woffp;
    const int wof = w * 1024;   // wave-private 32-row region (shorts) within a slot

#define STAGE_B(HALF)                                                                        \
    {                                                                                        \
        _Pragma("unroll")                                                                    \
        for (int i = 0; i < 4; ++i) {                                                        \
            __builtin_amdgcn_global_load_lds(                                                \
                (const __attribute__((address_space(1))) unsigned int*)(Bb + ((HALF) * 4 + w) * 4096 + i * 512 + lsw), \
                (__attribute__((address_space(3))) unsigned int*)&Bl[w * 2048 + i * 512], 16, 0, 0);                   \
        }                                                                                    \
    }

#define STAGE_STEP(S)                                                                        \
    {                                                                                        \
        __builtin_amdgcn_global_load_lds(                                                    \
            (const __attribute__((address_space(1))) unsigned int*)(A0 + (S) * 4096 + wof + lsw),        \
            (__attribute__((address_space(3))) unsigned int*)&Ar[(S) % 3][wof], 16, 0, 0);   \
        __builtin_amdgcn_global_load_lds(                                                    \
            (const __attribute__((address_space(1))) unsigned int*)(A0 + (S) * 4096 + wof + 512 + lsw),  \
            (__attribute__((address_space(3))) unsigned int*)&Ar[(S) % 3][wof + 512], 16, 0, 0);         \
    }

    STAGE_B(0)
    STAGE_STEP(0) STAGE_STEP(1)
    __syncthreads();   // drains: B half0 + A0,A1 resident

    f32x4 acc[2][4] = {};   // [i][j]

    // COMP: wait A(S) -> ds_read frags -> drain own ds_reads -> stage A(S+2) -> MFMAs
#define COMP_STEP(S, NW)                                                                     \
    {                                                                                        \
        asm volatile("s_waitcnt vmcnt(%0)" :: "i"(NW) : "memory");                           \
        bf16x8 bfr[4], af[2];                                                                \
        _Pragma("unroll") for (int j = 0; j < 4; ++j)                                        \
            bfr[j] = *(const bf16x8*)&Bl[((S) & 3) * 2048 + (j * 16 + lrow) * 32 + (lk ^ ckx) * 8]; \
        _Pragma("unroll") for (int i = 0; i < 2; ++i)                                        \
            af[i] = *(const bf16x8*)&Ar[(S) % 3][wof + i * 512 + lrow * 32 + (lk ^ ckx) * 8];\
        if ((S) + 2 < 8) {                                                                   \
            asm volatile("s_waitcnt lgkmcnt(0)" ::: "memory");                               \
            STAGE_STEP((S) + 2)                                                              \
        }                                                                                    \
        _Pragma("unroll") for (int i = 0; i < 2; ++i)                                        \
            _Pragma("unroll") for (int j = 0; j < 4; ++j)                                    \
                acc[i][j] = __builtin_amdgcn_mfma_f32_16x16x32_bf16(af[i], bfr[j], acc[i][j], 0, 0, 0); \
    }

    COMP_STEP(0, 4) COMP_STEP(1, 2) COMP_STEP(2, 2) COMP_STEP(3, 2)
    __syncthreads();          // all waves done reading B half0 (drains A4,A5 too)
    STAGE_B(1)
    __syncthreads();          // B half1 resident
    COMP_STEP(4, 4) COMP_STEP(5, 2) COMP_STEP(6, 2) COMP_STEP(7, 0)
#undef COMP_STEP
#undef STAGE_STEP
#undef STAGE_B

    if (bn < 8) {
        // epilogue: acc -> LDS [128][64] bf16 -> coalesced 16B stores, head-interleaved cols
        unsigned short* Cl = &Ar[0][0];   // 16KB of the 24KB ring
        __syncthreads();
#pragma unroll
        for (int j = 0; j < 4; ++j) {
            float bs = bias[bn * 64 + j * 16 + lrow];
#pragma unroll
            for (int i = 0; i < 2; ++i)
#pragma unroll
                for (int jj = 0; jj < 4; ++jj)
                    Cl[(w * 32 + i * 16 + lk * 4 + jj) * 64 + j * 16 + lrow] =
                        f2bf(acc[i][j][jj] + bs);
        }
        __syncthreads();
        // original col g = bn*64 + col8*8; K (bn<4): dst h*64+d; V (bn>=4): dst h*64+32+d
#pragma unroll
        for (int it = 0; it < 4; ++it) {
            int idx = it * 256 + tid;
            int row = idx >> 3, col8 = idx & 7;
            int dstcol = (bn < 4)
                ? (bn * 2 + (col8 >> 2)) * 64 + (col8 & 3) * 8
                : ((bn - 4) * 2 + (col8 >> 2)) * 64 + 32 + (col8 & 3) * 8;
            *(f32x4*)(C + (size_t)(chunk * 128 + row) * 512 + dstcol) =
                *(const f32x4*)&Cl[row * 64 + col8 * 8];
        }
    } else {
        // Foff epilogue: fp32 direct stores (no bias)
#pragma unroll
        for (int i = 0; i < 2; ++i)
#pragma unroll
            for (int j = 0; j < 4; ++j)
#pragma unroll
                for (int jj = 0; jj < 4; ++jj) {
                    int m = chunk * 128 + w * 32 + i * 16 + lk * 4 + jj;
                    Foff[(size_t)m * 64 + j * 16 + lrow] = acc[i][j][jj];
                }
    }
}

// ---------------- sample_offs: project points, bilinear-blend Foff, add qcat[:,256:320] ----------------
__global__ __launch_bounds__(384) void sample_offs(
    const float* __restrict__ points, const float* __restrict__ camM,
    const float* __restrict__ camb, const float* __restrict__ Foff,
    const float* __restrict__ qcat,
    float* __restrict__ offs, float* __restrict__ pxy) {
    int bk = blockIdx.x;
    int b = bk / 900;
    int cam = threadIdx.x >> 6, j = threadIdx.x & 63;
    int cid = cam * 7200 + bk;

    float p0 = points[(size_t)bk * 3 + 0];
    float p1 = points[(size_t)bk * 3 + 1];
    float p2 = points[(size_t)bk * 3 + 2];
    const float* M = camM + cam * 6;
    float s0 = M[0] * p0 + M[1] * p1 + M[2] * p2 + camb[cam * 2 + 0];
    float s1 = M[3] * p0 + M[4] * p1 + M[5] * p2 + camb[cam * 2 + 1];
    float px0 = (1.f / (1.f + expf(-s0))) * 32.f;
    float px1 = (1.f / (1.f + expf(-s1))) * 88.f;
    float gx = 2.f * px0 / 32.f - 1.f, gy = 2.f * px1 / 88.f - 1.f;
    float ix = (gx + 1.f) * 0.5f * 87.f;
    float iy = (gy + 1.f) * 0.5f * 31.f;
    float x0 = floorf(ix), y0 = floorf(iy), x1 = x0 + 1.f, y1 = y0 + 1.f;
    float wx1 = ix - x0, wx0 = x1 - ix, wy1 = iy - y0, wy0 = y1 - iy;
    float m00 = (x0 >= 0.f && x0 <= 87.f && y0 >= 0.f && y0 <= 31.f) ? 1.f : 0.f;
    float m01 = (x1 >= 0.f && x1 <= 87.f && y0 >= 0.f && y0 <= 31.f) ? 1.f : 0.f;
    float m10 = (x0 >= 0.f && x0 <= 87.f && y1 >= 0.f && y1 <= 31.f) ? 1.f : 0.f;
    float m11 = (x1 >= 0.f && x1 <= 87.f && y1 >= 0.f && y1 <= 31.f) ? 1.f : 0.f;
    float w00 = wx0 * wy0 * m00, w01 = wx1 * wy0 * m01, w10 = wx0 * wy1 * m10, w11 = wx1 * wy1 * m11;
    int xi0 = (int)fminf(fmaxf(x0, 0.f), 87.f);
    int xi1 = (int)fminf(fmaxf(x1, 0.f), 87.f);
    int yi0 = (int)fminf(fmaxf(y0, 0.f), 31.f);
    int yi1 = (int)fminf(fmaxf(y1, 0.f), 31.f);

    size_t base = (size_t)(cam * 8 + b) * 2816;
    const float* f00 = Foff + (base + yi0 * 88 + xi0) * 64;
    const float* f01 = Foff + (base + yi0 * 88 + xi1) * 64;
    const float* f10 = Foff + (base + yi1 * 88 + xi0) * 64;
    const float* f11 = Foff + (base + yi1 * 88 + xi1) * 64;

    float o = qcat[(size_t)bk * 320 + 256 + j]
            + w00 * f00[j] + w01 * f01[j] + w10 * f10[j] + w11 * f11[j];
    offs[(size_t)cid * 64 + j] = o;
    if (j == 0) { pxy[cid * 2 + 0] = px0; pxy[cid * 2 + 1] = px1; }
}

// ---------------- split-bf16 MFMA GEMM (fp32 A/B in): C = A@B^T + bias ----------------
template <bool SPLIT, bool C_BF16>
__global__ __launch_bounds__(256) void gemm_bf16(
    const float* __restrict__ A, long long aBatch,
    const float* __restrict__ B, const float* __restrict__ bias,
    void* __restrict__ Cv, long long cBatch,
    int M, int N, int K, int lda) {
    __shared__ __align__(16) unsigned short Ah[64][40];
    __shared__ __align__(16) unsigned short Bh[64][40];
    __shared__ __align__(16) unsigned short Al[(SPLIT ? 64 : 1)][40];
    __shared__ __align__(16) unsigned short Bl[(SPLIT ? 64 : 1)][40];

    const int tid = threadIdx.x;
    const int m0 = blockIdx.x * 64, n0 = blockIdx.y * 64;
    const int batch = blockIdx.z;
    const float* Ab = A + (size_t)batch * aBatch;
    const int lane = tid & 63, wave = tid >> 6;
    const int wr = wave & 1, wc = wave >> 1;
    const int lrow = lane & 15, lk = lane >> 4;

    f32x4 acc[2][2] = {};

    for (int kt = 0; kt < K; kt += 32) {
        if (kt) __syncthreads();
        {
            int c4 = (tid & 7) * 4;
#pragma unroll
            for (int rep = 0; rep < 2; rep++) {
                int r = (tid >> 3) + rep * 32;
                int m = m0 + r; if (m >= M) m = M - 1;
                f32x4 v = *(const f32x4*)(Ab + (size_t)m * lda + kt + c4);
#pragma unroll
                for (int q = 0; q < 4; q++) {
                    unsigned short h = f2bf(v[q]);
                    Ah[r][c4 + q] = h;
                    if (SPLIT) Al[r][c4 + q] = f2bf(v[q] - bf2f(h));
                }
            }
        }
        {
            int c4 = (tid & 7) * 4;
#pragma unroll
            for (int rep = 0; rep < 2; rep++) {
                int r = (tid >> 3) + rep * 32;
                f32x4 v = *(const f32x4*)(B + (size_t)(n0 + r) * K + kt + c4);
#pragma unroll
                for (int q = 0; q < 4; q++) {
                    unsigned short h = f2bf(v[q]);
                    Bh[r][c4 + q] = h;
                    if (SPLIT) Bl[r][c4 + q] = f2bf(v[q] - bf2f(h));
                }
            }
        }
        __syncthreads();

        bf16x8 a_h[2], b_h[2], a_l[2], b_l[2];
#pragma unroll
        for (int i = 0; i < 2; i++) {
            a_h[i] = *(const bf16x8*)&Ah[wr * 32 + i * 16 + lrow][lk * 8];
            b_h[i] = *(const bf16x8*)&Bh[wc * 32 + i * 16 + lrow][lk * 8];
            if (SPLIT) {
                a_l[i] = *(const bf16x8*)&Al[wr * 32 + i * 16 + lrow][lk * 8];
                b_l[i] = *(const bf16x8*)&Bl[wc * 32 + i * 16 + lrow][lk * 8];
            }
        }
#pragma unroll
        for (int i = 0; i < 2; i++)
#pragma unroll
            for (int j = 0; j < 2; j++) {
                acc[i][j] = __builtin_amdgcn_mfma_f32_16x16x32_bf16(a_h[i], b_h[j], acc[i][j], 0, 0, 0);
                if (SPLIT) {
                    acc[i][j] = __builtin_amdgcn_mfma_f32_16x16x32_bf16(a_h[i], b_l[j], acc[i][j], 0, 0, 0);
                    acc[i][j] = __builtin_amdgcn_mfma_f32_16x16x32_bf16(a_l[i], b_h[j], acc[i][j], 0, 0, 0);
                }
            }
    }

#pragma unroll
    for (int i = 0; i < 2; i++)
#pragma unroll
        for (int j = 0; j < 2; j++) {
            int n = n0 + wc * 32 + j * 16 + lrow;
            float bs = bias[n];
#pragma unroll
            for (int jj = 0; jj < 4; jj++) {
                int m = m0 + wr * 32 + i * 16 + lk * 4 + jj;
                if (m < M) {
                    float val = acc[i][j][jj] + bs;
                    if (C_BF16)
                        ((unsigned short*)Cv)[(size_t)batch * cBatch + (size_t)m * N + n] = f2bf(val);
                    else
                        ((float*)Cv)[(size_t)batch * cBatch + (size_t)m * N + n] = val;
                }
            }
        }
}

// ---------------- fused deformable attention (head-interleaved kv_t, x4 gathers) ----------------
__global__ __launch_bounds__(512) void attn_kernel(
    const float* __restrict__ qcat, const float* __restrict__ pxy,
    const float* __restrict__ offs, const unsigned short* __restrict__ kv_t,
    float* __restrict__ S) {
    int bk = blockIdx.x;            // b*900 + k
    int b = bk / 900, k = bk % 900;
    int h = threadIdx.x >> 6;       // wave = head
    int lane = threadIdx.x & 63;

    __shared__ __align__(16) float        ldsW[8][24][4];
    __shared__ __align__(16) unsigned int ldsI[8][24][4];
    __shared__ float ldsL[8][24];

    if (lane < 24) {
        int cam = lane >> 2, p = lane & 3;
        int cid = cam * 7200 + bk;
        float px0 = pxy[cid * 2 + 0], px1 = pxy[cid * 2 + 1];
        float o0 = offs[(size_t)cid * 64 + (h * 4 + p) * 2 + 0];
        float o1 = offs[(size_t)cid * 64 + (h * 4 + p) * 2 + 1];
        float pc0 = px0 + o0 * (1.f / 32.f);
        float pc1 = px1 + o1 * (1.f / 88.f);
        float gx = 2.f * (pc0 * (1.f / 32.f)) - 1.f;
        float gy = 2.f * (pc1 * (1.f / 88.f)) - 1.f;
        float ix = (gx + 1.f) * 0.5f * 87.f;
        float iy = (gy + 1.f) * 0.5f * 31.f;
        float x0 = floorf(ix), y0 = floorf(iy), x1 = x0 + 1.f, y1 = y0 + 1.f;
        float wx1 = ix - x0, wx0 = x1 - ix, wy1 = iy - y0, wy0 = y1 - iy;
        float m00 = (x0 >= 0.f && x0 <= 87.f && y0 >= 0.f && y0 <= 31.f) ? 1.f : 0.f;
        float m01 = (x1 >= 0.f && x1 <= 87.f && y0 >= 0.f && y0 <= 31.f) ? 1.f : 0.f;
        float m10 = (x0 >= 0.f && x0 <= 87.f && y1 >= 0.f && y1 <= 31.f) ? 1.f : 0.f;
        float m11 = (x1 >= 0.f && x1 <= 87.f && y1 >= 0.f && y1 <= 31.f) ? 1.f : 0.f;
        int xi0 = (int)fminf(fmaxf(x0, 0.f), 87.f);
        int xi1 = (int)fminf(fmaxf(x1, 0.f), 87.f);
        int yi0 = (int)fminf(fmaxf(y0, 0.f), 31.f);
        int yi1 = (int)fminf(fmaxf(y1, 0.f), 31.f);
        unsigned int img = (unsigned int)(cam * 8 + b) * 2816u;
        ldsW[h][lane][0] = wx0 * wy0 * m00;
        ldsW[h][lane][1] = wx1 * wy0 * m01;
        ldsW[h][lane][2] = wx0 * wy1 * m10;
        ldsW[h][lane][3] = wx1 * wy1 * m11;
        ldsI[h][lane][0] = (img + yi0 * 88 + xi0) * 1024u;
        ldsI[h][lane][1] = (img + yi0 * 88 + xi1) * 1024u;
        ldsI[h][lane][2] = (img + yi1 * 88 + xi0) * 1024u;
        ldsI[h][lane][3] = (img + yi1 * 88 + xi1) * 1024u;
    }
    __syncthreads();

    const int p8 = lane >> 3, dlane = lane & 7;
    const int chB = h * 128 + dlane * 16;    // byte offset within pixel row
    const char* kvb = (const char*)kv_t;

    f32x4 qa = *(const f32x4*)(qcat + (size_t)bk * 320 + h * 32 + (dlane & 3) * 8);
    f32x4 qb = *(const f32x4*)(qcat + (size_t)bk * 320 + h * 32 + (dlane & 3) * 8 + 4);

    float vr[3][8];
    const float inv_sqrt = 0.17677669529663687f;
#pragma unroll
    for (int it = 0; it < 3; ++it) {
        int l = it * 8 + p8;
        f32x4 w = *(const f32x4*)ldsW[h][l];
        unsigned int i0 = ldsI[h][l][0], i1 = ldsI[h][l][1];
        unsigned int i2 = ldsI[h][l][2], i3 = ldsI[h][l][3];
        u32x4 u0 = *(const u32x4*)(kvb + i0 + chB);
        u32x4 u1 = *(const u32x4*)(kvb + i1 + chB);
        u32x4 u2 = *(const u32x4*)(kvb + i2 + chB);
        u32x4 u3 = *(const u32x4*)(kvb + i3 + chB);
#pragma unroll
        for (int q = 0; q < 4; ++q) {
            vr[it][2 * q] = w[0] * u2f(u0[q] << 16) + w[1] * u2f(u1[q] << 16)
                          + w[2] * u2f(u2[q] << 16) + w[3] * u2f(u3[q] << 16);
            vr[it][2 * q + 1] = w[0] * u2f(u0[q] & 0xFFFF0000u) + w[1] * u2f(u1[q] & 0xFFFF0000u)
                              + w[2] * u2f(u2[q] & 0xFFFF0000u) + w[3] * u2f(u3[q] & 0xFFFF0000u);
        }
        float t = qa[0] * vr[it][0] + qa[1] * vr[it][1] + qa[2] * vr[it][2] + qa[3] * vr[it][3]
                + qb[0] * vr[it][4] + qb[1] * vr[it][5] + qb[2] * vr[it][6] + qb[3] * vr[it][7];
        t += __shfl_xor(t, 1);
        t += __shfl_xor(t, 2);
        if (dlane == 0) ldsL[h][l] = t * inv_sqrt;
    }
    __syncthreads();

    float mx = -1e30f;
#pragma unroll
    for (int l = 0; l < 24; l++) mx = fmaxf(mx, ldsL[h][l]);
    float ssum = 0.f;
    float at3[3];
#pragma unroll
    for (int l = 0; l < 24; l++) {
        float e = __expf(ldsL[h][l] - mx);
        ssum += e;
        if ((l & 7) == p8) at3[l >> 3] = e;
    }
    float inv = 1.f / ssum;

    float o[8];
#pragma unroll
    for (int j = 0; j < 8; ++j)
        o[j] = at3[0] * vr[0][j] + at3[1] * vr[1][j] + at3[2] * vr[2][j];
#pragma unroll
    for (int j = 0; j < 8; ++j) {
        o[j] += __shfl_xor(o[j], 8);
        o[j] += __shfl_xor(o[j], 16);
        o[j] += __shfl_xor(o[j], 32);
    }
    if (p8 == 0 && dlane >= 4) {
        int d0 = (dlane - 4) * 8;
        f32x4 v0, v1;
        v0[0] = o[0] * inv; v0[1] = o[1] * inv; v0[2] = o[2] * inv; v0[3] = o[3] * inv;
        v1[0] = o[4] * inv; v1[1] = o[5] * inv; v1[2] = o[6] * inv; v1[3] = o[7] * inv;
        float* dst = &S[(size_t)b * 230400 + (size_t)h * 28800 + k * 32 + d0];
        *(f32x4*)dst = v0;
        *(f32x4*)(dst + 4) = v1;
    }
}

extern "C" void kernel_launch(void* const* d_in, const int* in_sizes, int n_in,
                              void* d_out, int out_size, void* d_ws, size_t ws_size,
                              hipStream_t stream) {
    const float* query    = (const float*)d_in[0];
    const float* points   = (const float*)d_in[1];
    const float* features = (const float*)d_in[2];
    const float* camM     = (const float*)d_in[3];
    const float* camb     = (const float*)d_in[4];
    const float* W_off    = (const float*)d_in[5];
    const float* b_off    = (const float*)d_in[6];
    const float* W_q      = (const float*)d_in[7];
    const float* b_q      = (const float*)d_in[8];
    const float* W_k      = (const float*)d_in[9];
    const float* b_k      = (const float*)d_in[10];
    const float* W_v      = (const float*)d_in[11];
    const float* b_v      = (const float*)d_in[12];
    const float* W_o      = (const float*)d_in[13];
    const float* b_o      = (const float*)d_in[14];

    char* ws = (char*)d_ws;
    unsigned short* feat_t = (unsigned short*)ws; ws += 69206016;   // blocked [1056][8][128][32] bf16
    unsigned short* kv_t   = (unsigned short*)ws; ws += 138412032;  // [135168][8 heads][64] bf16
    float* Foff   = (float*)ws; ws += 34603008;                     // [135168][64]
    float* offs   = (float*)ws; ws += 11059200;                     // [43200][64]
    float* pxy    = (float*)ws; ws += 345600;                       // [43200][2]
    float* qcat   = (float*)ws; ws += 9216000;                      // [7200][320] = [q_proj | qWoff]
    float* S      = (float*)ws; ws += 7372800;                      // [8][230400] scrambled
    unsigned short* Wkv = (unsigned short*)ws; ws += 524288;        // blocked [4][8][128][32] bf16
    float* bkv    = (float*)ws; ws += 2048;                         // [512]
    unsigned short* Woffp = (unsigned short*)ws; ws += 65536;       // blocked [8 kt][4096] bf16
    float* Wcat   = (float*)ws; ws += 327680;                       // [320][256] fp32
    float* bcat   = (float*)ws; ws += 1280;                         // [320]

    prep_all<<<512, 256, 0, stream>>>(W_k, b_k, W_v, b_v, W_q, b_q, W_off, b_off,
                                      Wkv, bkv, Woffp, Wcat, bcat);
    transpose_feat<<<dim3(88, 8, 48), 256, 0, stream>>>(features, feat_t);
    // kv_t (bn 0-7, head-interleaved) + Foff (bn 8) : 40KB counted-vmcnt pipeline
    gemm_kv2<<<9504, 256, 0, stream>>>(feat_t, Wkv, Woffp, bkv, kv_t, Foff);
    // qcat = query @ [W_q|W_off]^T + [b_q|b_off] : [7200 x 320]
    gemm_bf16<true, false><<<dim3(113, 5, 1), 256, 0, stream>>>(
        query, 0, Wcat, bcat, qcat, 0, 7200, 320, 256, 256);
    // offs[cid][64] = qcat[:,256:] + bilinear(Foff); pxy
    sample_offs<<<7200, 384, 0, stream>>>(points, camM, camb, Foff, qcat, offs, pxy);
    attn_kernel<<<7200, 512, 0, stream>>>(qcat, pxy, offs, kv_t, S);
    // out = S @ W_o^T + b_o : [7200 x 256]
    gemm_bf16<true, false><<<dim3(113, 4, 1), 256, 0, stream>>>(
        S, 0, W_o, b_o, d_out, 0, 7200, 256, 256, 256);
}

// Round 16
// 233.029 us; speedup vs baseline: 1.1146x; 1.0187x over previous
//
#include <hip/hip_runtime.h>

typedef __attribute__((ext_vector_type(4))) float f32x4;
typedef __attribute__((ext_vector_type(8))) short bf16x8;
typedef __attribute__((ext_vector_type(4))) unsigned int u32x4;

__device__ __forceinline__ unsigned short f2bf(float f) {
    union { float f; unsigned int u; } x; x.f = f;
    unsigned int u = x.u;
    return (unsigned short)((u + 0x7FFFu + ((u >> 16) & 1u)) >> 16);
}
__device__ __forceinline__ float bf2f(unsigned short b) {
    union { unsigned int u; float f; } x; x.u = ((unsigned int)b) << 16;
    return x.f;
}
__device__ __forceinline__ float u2f(unsigned int u) {
    union { unsigned int u; float f; } x; x.u = u; return x.f;
}

// blocked layout (row r, ch k), 128-row blocks: ((r>>7)*8 + (k>>5))*4096 + (r&127)*32 + (k&31)
// LDS tiles: 16B-chunk XOR swizzle, chunk c of row r at c ^ ((r>>1)&3); staging pre-swizzles
// the per-lane GLOBAL source (LDS dest linear); reads use chunk lk ^ ((lrow>>1)&3).
// kv_t layout: [pixel][head][K ch 0-31 | V ch 0-31] bf16 (head-interleaved, 128B per head).

// ---------------- prep (merged): Wkv blocked bf16, Woff blocked bf16, Wcat=[Wq|Woff] fp32 ----------------
__global__ void prep_all(const float* __restrict__ Wk, const float* __restrict__ bk,
                         const float* __restrict__ Wv, const float* __restrict__ bv,
                         const float* __restrict__ Wq, const float* __restrict__ bq,
                         const float* __restrict__ Woff, const float* __restrict__ boff,
                         unsigned short* __restrict__ Wkv, float* __restrict__ bkv,
                         unsigned short* __restrict__ Woffp,
                         float* __restrict__ Wcat, float* __restrict__ bcat) {
    int i = blockIdx.x * 256 + threadIdx.x;   // grid 512*256 = 131072
    if (i < 512 * 256) {
        int n = i >> 8, k = i & 255;
        float v = (n < 256) ? Wk[i] : Wv[i - 65536];
        Wkv[((size_t)(n >> 7) * 8 + (k >> 5)) * 4096 + (n & 127) * 32 + (k & 31)] = f2bf(v);
    }
    if (i < 512) bkv[i] = (i < 256) ? bk[i] : bv[i - 256];
    if (i < 64 * 256) {
        int n = i >> 8, k = i & 255;
        Woffp[(size_t)(k >> 5) * 4096 + n * 32 + (k & 31)] = f2bf(Woff[i]);
    }
    if (i < 320 * 256) Wcat[i] = (i < 65536) ? Wq[i] : Woff[i - 65536];
    if (i < 320) bcat[i] = (i < 256) ? bq[i] : boff[i - 256];
}

// ---------------- transpose features [48][256][2816] -> bf16 blocked ----------------
__global__ __launch_bounds__(256) void transpose_feat(const float* __restrict__ src,
                                                      unsigned short* __restrict__ dst) {
    __shared__ float tile[32][33];
    int img = blockIdx.z;
    int p0 = blockIdx.x * 32;   // pixel
    int d0 = blockIdx.y * 32;   // channel
    int tx = threadIdx.x & 31, ty = threadIdx.x >> 5;
    const float* s = src + (size_t)img * 256 * 2816;
#pragma unroll
    for (int i = 0; i < 4; i++) tile[ty + 8 * i][tx] = s[(size_t)(d0 + ty + 8 * i) * 2816 + p0 + tx];
    __syncthreads();
    int m = img * 2816 + p0;
    unsigned short* o = dst + ((size_t)(m >> 7) * 8 + (d0 >> 5)) * 4096 + (m & 127) * 32;
#pragma unroll
    for (int i = 0; i < 4; i++) o[(ty + 8 * i) * 32 + tx] = f2bf(tile[tx][ty + 8 * i]);
}

// ---------------- kv+off projection: counted-vmcnt pipelined GEMM, 40KB LDS (4 blocks/CU) ----------------
// bn 0..7: kv_t (head-interleaved cols) = A @ Wkv^T + bkv (64 original cols per bn)
// bn 8   : Foff[135168][64] fp32 = A @ Woff^T (no bias)
__global__ __launch_bounds__(256) void gemm_kv2(
    const unsigned short* __restrict__ A,
    const unsigned short* __restrict__ Wkv,
    const unsigned short* __restrict__ Woffp,
    const float* __restrict__ bias,
    unsigned short* __restrict__ C,
    float* __restrict__ Foff) {
    __shared__ __align__(16) unsigned short Bl[8192];     // 16KB: [kt&3][64r][32c] (swizzled)
    __shared__ __align__(16) unsigned short Ar[3][4096];  // ring: [slot][128r][32c] (swizzled)

    const int tid = threadIdx.x, lane = tid & 63, w = tid >> 6;
    const int lrow = lane & 15, lk = lane >> 4;
    const int lsw = (lane >> 2) * 32 + (((lane & 3) ^ ((lane >> 3) & 3)) * 8);
    const int ckx = ((lrow >> 1) & 3);    // read-side chunk xor
    const int bid = blockIdx.x;
    const int wgid = (bid & 7) * 1188 + (bid >> 3);  // XCD swizzle (9504 = 8*1188)
    const int chunk = wgid / 9, bn = wgid % 9;       // chunk: m-block 0..1055, bn: 0..8

    const unsigned short* A0 = A + (size_t)chunk * 32768;
    const unsigned short* Bb = (bn < 8)
        ? Wkv + (size_t)(bn >> 1) * 32768 + (bn & 1) * 2048
        : Woffp;
    const int wof = w * 1024;   // wave-private 32-row region (shorts) within a slot

#define STAGE_B(HALF)                                                                        \
    {                                                                                        \
        _Pragma("unroll")                                                                    \
        for (int i = 0; i < 4; ++i) {                                                        \
            __builtin_amdgcn_global_load_lds(                                                \
                (const __attribute__((address_space(1))) unsigned int*)(Bb + ((HALF) * 4 + w) * 4096 + i * 512 + lsw), \
                (__attribute__((address_space(3))) unsigned int*)&Bl[w * 2048 + i * 512], 16, 0, 0);                   \
        }                                                                                    \
    }

#define STAGE_STEP(S)                                                                        \
    {                                                                                        \
        __builtin_amdgcn_global_load_lds(                                                    \
            (const __attribute__((address_space(1))) unsigned int*)(A0 + (S) * 4096 + wof + lsw),        \
            (__attribute__((address_space(3))) unsigned int*)&Ar[(S) % 3][wof], 16, 0, 0);   \
        __builtin_amdgcn_global_load_lds(                                                    \
            (const __attribute__((address_space(1))) unsigned int*)(A0 + (S) * 4096 + wof + 512 + lsw),  \
            (__attribute__((address_space(3))) unsigned int*)&Ar[(S) % 3][wof + 512], 16, 0, 0);         \
    }

    STAGE_B(0)
    STAGE_STEP(0) STAGE_STEP(1)
    __syncthreads();   // drains: B half0 + A0,A1 resident

    f32x4 acc[2][4] = {};   // [i][j]

    // COMP: wait A(S) -> ds_read frags -> drain own ds_reads -> stage A(S+2) -> MFMAs
#define COMP_STEP(S, NW)                                                                     \
    {                                                                                        \
        asm volatile("s_waitcnt vmcnt(%0)" :: "i"(NW) : "memory");                           \
        bf16x8 bfr[4], af[2];                                                                \
        _Pragma("unroll") for (int j = 0; j < 4; ++j)                                        \
            bfr[j] = *(const bf16x8*)&Bl[((S) & 3) * 2048 + (j * 16 + lrow) * 32 + (lk ^ ckx) * 8]; \
        _Pragma("unroll") for (int i = 0; i < 2; ++i)                                        \
            af[i] = *(const bf16x8*)&Ar[(S) % 3][wof + i * 512 + lrow * 32 + (lk ^ ckx) * 8];\
        if ((S) + 2 < 8) {                                                                   \
            asm volatile("s_waitcnt lgkmcnt(0)" ::: "memory");                               \
            STAGE_STEP((S) + 2)                                                              \
        }                                                                                    \
        _Pragma("unroll") for (int i = 0; i < 2; ++i)                                        \
            _Pragma("unroll") for (int j = 0; j < 4; ++j)                                    \
                acc[i][j] = __builtin_amdgcn_mfma_f32_16x16x32_bf16(af[i], bfr[j], acc[i][j], 0, 0, 0); \
    }

    COMP_STEP(0, 4) COMP_STEP(1, 2) COMP_STEP(2, 2) COMP_STEP(3, 2)
    __syncthreads();          // all waves done reading B half0 (drains A4,A5 too)
    STAGE_B(1)
    __syncthreads();          // B half1 resident
    COMP_STEP(4, 4) COMP_STEP(5, 2) COMP_STEP(6, 2) COMP_STEP(7, 0)
#undef COMP_STEP
#undef STAGE_STEP
#undef STAGE_B

    if (bn < 8) {
        // epilogue: acc -> LDS [128][64] bf16 -> coalesced 16B stores, head-interleaved cols
        unsigned short* Cl = &Ar[0][0];   // 16KB of the 24KB ring
        __syncthreads();
#pragma unroll
        for (int j = 0; j < 4; ++j) {
            float bs = bias[bn * 64 + j * 16 + lrow];
#pragma unroll
            for (int i = 0; i < 2; ++i)
#pragma unroll
                for (int jj = 0; jj < 4; ++jj)
                    Cl[(w * 32 + i * 16 + lk * 4 + jj) * 64 + j * 16 + lrow] =
                        f2bf(acc[i][j][jj] + bs);
        }
        __syncthreads();
        // original col g = bn*64 + col8*8; K (bn<4): dst h*64+d; V (bn>=4): dst h*64+32+d
#pragma unroll
        for (int it = 0; it < 4; ++it) {
            int idx = it * 256 + tid;
            int row = idx >> 3, col8 = idx & 7;
            int dstcol = (bn < 4)
                ? (bn * 2 + (col8 >> 2)) * 64 + (col8 & 3) * 8
                : ((bn - 4) * 2 + (col8 >> 2)) * 64 + 32 + (col8 & 3) * 8;
            *(f32x4*)(C + (size_t)(chunk * 128 + row) * 512 + dstcol) =
                *(const f32x4*)&Cl[row * 64 + col8 * 8];
        }
    } else {
        // Foff epilogue: fp32 direct stores (no bias)
#pragma unroll
        for (int i = 0; i < 2; ++i)
#pragma unroll
            for (int j = 0; j < 4; ++j)
#pragma unroll
                for (int jj = 0; jj < 4; ++jj) {
                    int m = chunk * 128 + w * 32 + i * 16 + lk * 4 + jj;
                    Foff[(size_t)m * 64 + j * 16 + lrow] = acc[i][j][jj];
                }
    }
}

// ---------------- split-bf16 MFMA GEMM (fp32 A/B in): C = A@B^T + bias ----------------
template <bool SPLIT, bool C_BF16>
__global__ __launch_bounds__(256) void gemm_bf16(
    const float* __restrict__ A, long long aBatch,
    const float* __restrict__ B, const float* __restrict__ bias,
    void* __restrict__ Cv, long long cBatch,
    int M, int N, int K, int lda) {
    __shared__ __align__(16) unsigned short Ah[64][40];
    __shared__ __align__(16) unsigned short Bh[64][40];
    __shared__ __align__(16) unsigned short Al[(SPLIT ? 64 : 1)][40];
    __shared__ __align__(16) unsigned short Bl[(SPLIT ? 64 : 1)][40];

    const int tid = threadIdx.x;
    const int m0 = blockIdx.x * 64, n0 = blockIdx.y * 64;
    const int batch = blockIdx.z;
    const float* Ab = A + (size_t)batch * aBatch;
    const int lane = tid & 63, wave = tid >> 6;
    const int wr = wave & 1, wc = wave >> 1;
    const int lrow = lane & 15, lk = lane >> 4;

    f32x4 acc[2][2] = {};

    for (int kt = 0; kt < K; kt += 32) {
        if (kt) __syncthreads();
        {
            int c4 = (tid & 7) * 4;
#pragma unroll
            for (int rep = 0; rep < 2; rep++) {
                int r = (tid >> 3) + rep * 32;
                int m = m0 + r; if (m >= M) m = M - 1;
                f32x4 v = *(const f32x4*)(Ab + (size_t)m * lda + kt + c4);
#pragma unroll
                for (int q = 0; q < 4; q++) {
                    unsigned short h = f2bf(v[q]);
                    Ah[r][c4 + q] = h;
                    if (SPLIT) Al[r][c4 + q] = f2bf(v[q] - bf2f(h));
                }
            }
        }
        {
            int c4 = (tid & 7) * 4;
#pragma unroll
            for (int rep = 0; rep < 2; rep++) {
                int r = (tid >> 3) + rep * 32;
                f32x4 v = *(const f32x4*)(B + (size_t)(n0 + r) * K + kt + c4);
#pragma unroll
                for (int q = 0; q < 4; q++) {
                    unsigned short h = f2bf(v[q]);
                    Bh[r][c4 + q] = h;
                    if (SPLIT) Bl[r][c4 + q] = f2bf(v[q] - bf2f(h));
                }
            }
        }
        __syncthreads();

        bf16x8 a_h[2], b_h[2], a_l[2], b_l[2];
#pragma unroll
        for (int i = 0; i < 2; i++) {
            a_h[i] = *(const bf16x8*)&Ah[wr * 32 + i * 16 + lrow][lk * 8];
            b_h[i] = *(const bf16x8*)&Bh[wc * 32 + i * 16 + lrow][lk * 8];
            if (SPLIT) {
                a_l[i] = *(const bf16x8*)&Al[wr * 32 + i * 16 + lrow][lk * 8];
                b_l[i] = *(const bf16x8*)&Bl[wc * 32 + i * 16 + lrow][lk * 8];
            }
        }
#pragma unroll
        for (int i = 0; i < 2; i++)
#pragma unroll
            for (int j = 0; j < 2; j++) {
                acc[i][j] = __builtin_amdgcn_mfma_f32_16x16x32_bf16(a_h[i], b_h[j], acc[i][j], 0, 0, 0);
                if (SPLIT) {
                    acc[i][j] = __builtin_amdgcn_mfma_f32_16x16x32_bf16(a_h[i], b_l[j], acc[i][j], 0, 0, 0);
                    acc[i][j] = __builtin_amdgcn_mfma_f32_16x16x32_bf16(a_l[i], b_h[j], acc[i][j], 0, 0, 0);
                }
            }
    }

#pragma unroll
    for (int i = 0; i < 2; i++)
#pragma unroll
        for (int j = 0; j < 2; j++) {
            int n = n0 + wc * 32 + j * 16 + lrow;
            float bs = bias[n];
#pragma unroll
            for (int jj = 0; jj < 4; jj++) {
                int m = m0 + wr * 32 + i * 16 + lk * 4 + jj;
                if (m < M) {
                    float val = acc[i][j][jj] + bs;
                    if (C_BF16)
                        ((unsigned short*)Cv)[(size_t)batch * cBatch + (size_t)m * N + n] = f2bf(val);
                    else
                        ((float*)Cv)[(size_t)batch * cBatch + (size_t)m * N + n] = val;
                }
            }
        }
}

// ---------------- fused deformable attention (projection + offsets fused in) ----------------
// block = bk, 512 threads, wave = head. Phase 0 (lane<24): per (cam,point) compute the
// camera projection, gather Foff (offset features), add qcat[:,256+*] -> offset point;
// then bilinear weights + kv_t corner byte-offsets into LDS.
__global__ __launch_bounds__(512) void attn_kernel(
    const float* __restrict__ qcat, const float* __restrict__ points,
    const float* __restrict__ camM, const float* __restrict__ camb,
    const float* __restrict__ Foff, const unsigned short* __restrict__ kv_t,
    float* __restrict__ S) {
    int bk = blockIdx.x;            // b*900 + k
    int b = bk / 900, k = bk % 900;
    int h = threadIdx.x >> 6;       // wave = head
    int lane = threadIdx.x & 63;

    __shared__ __align__(16) float        ldsW[8][24][4];
    __shared__ __align__(16) unsigned int ldsI[8][24][4];
    __shared__ float ldsL[8][24];

    if (lane < 24) {
        int cam = lane >> 2, p = lane & 3;
        // ---- base projection (was camf/sample_offs) ----
        float pt0 = points[(size_t)bk * 3 + 0];
        float pt1 = points[(size_t)bk * 3 + 1];
        float pt2 = points[(size_t)bk * 3 + 2];
        const float* M = camM + cam * 6;
        float s0 = M[0] * pt0 + M[1] * pt1 + M[2] * pt2 + camb[cam * 2 + 0];
        float s1 = M[3] * pt0 + M[4] * pt1 + M[5] * pt2 + camb[cam * 2 + 1];
        float px0 = (1.f / (1.f + expf(-s0))) * 32.f;
        float px1 = (1.f / (1.f + expf(-s1))) * 88.f;
        // ---- base-point bilinear for Foff gather (exact sample_offs math) ----
        {
            float gxb = 2.f * px0 / 32.f - 1.f, gyb = 2.f * px1 / 88.f - 1.f;
            float ixb = (gxb + 1.f) * 0.5f * 87.f;
            float iyb = (gyb + 1.f) * 0.5f * 31.f;
            float xb0 = floorf(ixb), yb0 = floorf(iyb), xb1 = xb0 + 1.f, yb1 = yb0 + 1.f;
            float wxb1 = ixb - xb0, wxb0 = xb1 - ixb, wyb1 = iyb - yb0, wyb0 = yb1 - iyb;
            float mb00 = (xb0 >= 0.f && xb0 <= 87.f && yb0 >= 0.f && yb0 <= 31.f) ? 1.f : 0.f;
            float mb01 = (xb1 >= 0.f && xb1 <= 87.f && yb0 >= 0.f && yb0 <= 31.f) ? 1.f : 0.f;
            float mb10 = (xb0 >= 0.f && xb0 <= 87.f && yb1 >= 0.f && yb1 <= 31.f) ? 1.f : 0.f;
            float mb11 = (xb1 >= 0.f && xb1 <= 87.f && yb1 >= 0.f && yb1 <= 31.f) ? 1.f : 0.f;
            float wb00 = wxb0 * wyb0 * mb00, wb01 = wxb1 * wyb0 * mb01;
            float wb10 = wxb0 * wyb1 * mb10, wb11 = wxb1 * wyb1 * mb11;
            int xib0 = (int)fminf(fmaxf(xb0, 0.f), 87.f);
            int xib1 = (int)fminf(fmaxf(xb1, 0.f), 87.f);
            int yib0 = (int)fminf(fmaxf(yb0, 0.f), 31.f);
            int yib1 = (int)fminf(fmaxf(yb1, 0.f), 31.f);
            size_t base = (size_t)(cam * 8 + b) * 2816;
            const float* f00 = Foff + (base + yib0 * 88 + xib0) * 64;
            const float* f01 = Foff + (base + yib0 * 88 + xib1) * 64;
            const float* f10 = Foff + (base + yib1 * 88 + xib0) * 64;
            const float* f11 = Foff + (base + yib1 * 88 + xib1) * 64;
            int j0 = (h * 4 + p) * 2;
            float o0 = qcat[(size_t)bk * 320 + 256 + j0]
                     + wb00 * f00[j0] + wb01 * f01[j0] + wb10 * f10[j0] + wb11 * f11[j0];
            float o1 = qcat[(size_t)bk * 320 + 256 + j0 + 1]
                     + wb00 * f00[j0 + 1] + wb01 * f01[j0 + 1] + wb10 * f10[j0 + 1] + wb11 * f11[j0 + 1];
            // ---- offset point -> kv_t bilinear (existing math) ----
            float pc0 = px0 + o0 * (1.f / 32.f);
            float pc1 = px1 + o1 * (1.f / 88.f);
            float gx = 2.f * (pc0 * (1.f / 32.f)) - 1.f;
            float gy = 2.f * (pc1 * (1.f / 88.f)) - 1.f;
            float ix = (gx + 1.f) * 0.5f * 87.f;
            float iy = (gy + 1.f) * 0.5f * 31.f;
            float x0 = floorf(ix), y0 = floorf(iy), x1 = x0 + 1.f, y1 = y0 + 1.f;
            float wx1 = ix - x0, wx0 = x1 - ix, wy1 = iy - y0, wy0 = y1 - iy;
            float m00 = (x0 >= 0.f && x0 <= 87.f && y0 >= 0.f && y0 <= 31.f) ? 1.f : 0.f;
            float m01 = (x1 >= 0.f && x1 <= 87.f && y0 >= 0.f && y0 <= 31.f) ? 1.f : 0.f;
            float m10 = (x0 >= 0.f && x0 <= 87.f && y1 >= 0.f && y1 <= 31.f) ? 1.f : 0.f;
            float m11 = (x1 >= 0.f && x1 <= 87.f && y1 >= 0.f && y1 <= 31.f) ? 1.f : 0.f;
            int xi0 = (int)fminf(fmaxf(x0, 0.f), 87.f);
            int xi1 = (int)fminf(fmaxf(x1, 0.f), 87.f);
            int yi0 = (int)fminf(fmaxf(y0, 0.f), 31.f);
            int yi1 = (int)fminf(fmaxf(y1, 0.f), 31.f);
            unsigned int img = (unsigned int)(cam * 8 + b) * 2816u;
            ldsW[h][lane][0] = wx0 * wy0 * m00;
            ldsW[h][lane][1] = wx1 * wy0 * m01;
            ldsW[h][lane][2] = wx0 * wy1 * m10;
            ldsW[h][lane][3] = wx1 * wy1 * m11;
            ldsI[h][lane][0] = (img + yi0 * 88 + xi0) * 1024u;
            ldsI[h][lane][1] = (img + yi0 * 88 + xi1) * 1024u;
            ldsI[h][lane][2] = (img + yi1 * 88 + xi0) * 1024u;
            ldsI[h][lane][3] = (img + yi1 * 88 + xi1) * 1024u;
        }
    }
    __syncthreads();

    const int p8 = lane >> 3, dlane = lane & 7;
    const int chB = h * 128 + dlane * 16;    // byte offset within pixel row
    const char* kvb = (const char*)kv_t;

    f32x4 qa = *(const f32x4*)(qcat + (size_t)bk * 320 + h * 32 + (dlane & 3) * 8);
    f32x4 qb = *(const f32x4*)(qcat + (size_t)bk * 320 + h * 32 + (dlane & 3) * 8 + 4);

    float vr[3][8];
    const float inv_sqrt = 0.17677669529663687f;
#pragma unroll
    for (int it = 0; it < 3; ++it) {
        int l = it * 8 + p8;
        f32x4 w = *(const f32x4*)ldsW[h][l];
        unsigned int i0 = ldsI[h][l][0], i1 = ldsI[h][l][1];
        unsigned int i2 = ldsI[h][l][2], i3 = ldsI[h][l][3];
        u32x4 u0 = *(const u32x4*)(kvb + i0 + chB);
        u32x4 u1 = *(const u32x4*)(kvb + i1 + chB);
        u32x4 u2 = *(const u32x4*)(kvb + i2 + chB);
        u32x4 u3 = *(const u32x4*)(kvb + i3 + chB);
#pragma unroll
        for (int q = 0; q < 4; ++q) {
            vr[it][2 * q] = w[0] * u2f(u0[q] << 16) + w[1] * u2f(u1[q] << 16)
                          + w[2] * u2f(u2[q] << 16) + w[3] * u2f(u3[q] << 16);
            vr[it][2 * q + 1] = w[0] * u2f(u0[q] & 0xFFFF0000u) + w[1] * u2f(u1[q] & 0xFFFF0000u)
                              + w[2] * u2f(u2[q] & 0xFFFF0000u) + w[3] * u2f(u3[q] & 0xFFFF0000u);
        }
        float t = qa[0] * vr[it][0] + qa[1] * vr[it][1] + qa[2] * vr[it][2] + qa[3] * vr[it][3]
                + qb[0] * vr[it][4] + qb[1] * vr[it][5] + qb[2] * vr[it][6] + qb[3] * vr[it][7];
        t += __shfl_xor(t, 1);
        t += __shfl_xor(t, 2);
        if (dlane == 0) ldsL[h][l] = t * inv_sqrt;
    }
    __syncthreads();

    float mx = -1e30f;
#pragma unroll
    for (int l = 0; l < 24; l++) mx = fmaxf(mx, ldsL[h][l]);
    float ssum = 0.f;
    float at3[3];
#pragma unroll
    for (int l = 0; l < 24; l++) {
        float e = __expf(ldsL[h][l] - mx);
        ssum += e;
        if ((l & 7) == p8) at3[l >> 3] = e;
    }
    float inv = 1.f / ssum;

    float o[8];
#pragma unroll
    for (int j = 0; j < 8; ++j)
        o[j] = at3[0] * vr[0][j] + at3[1] * vr[1][j] + at3[2] * vr[2][j];
#pragma unroll
    for (int j = 0; j < 8; ++j) {
        o[j] += __shfl_xor(o[j], 8);
        o[j] += __shfl_xor(o[j], 16);
        o[j] += __shfl_xor(o[j], 32);
    }
    if (p8 == 0 && dlane >= 4) {
        int d0 = (dlane - 4) * 8;
        f32x4 v0, v1;
        v0[0] = o[0] * inv; v0[1] = o[1] * inv; v0[2] = o[2] * inv; v0[3] = o[3] * inv;
        v1[0] = o[4] * inv; v1[1] = o[5] * inv; v1[2] = o[6] * inv; v1[3] = o[7] * inv;
        float* dst = &S[(size_t)b * 230400 + (size_t)h * 28800 + k * 32 + d0];
        *(f32x4*)dst = v0;
        *(f32x4*)(dst + 4) = v1;
    }
}

extern "C" void kernel_launch(void* const* d_in, const int* in_sizes, int n_in,
                              void* d_out, int out_size, void* d_ws, size_t ws_size,
                              hipStream_t stream) {
    const float* query    = (const float*)d_in[0];
    const float* points   = (const float*)d_in[1];
    const float* features = (const float*)d_in[2];
    const float* camM     = (const float*)d_in[3];
    const float* camb     = (const float*)d_in[4];
    const float* W_off    = (const float*)d_in[5];
    const float* b_off    = (const float*)d_in[6];
    const float* W_q      = (const float*)d_in[7];
    const float* b_q      = (const float*)d_in[8];
    const float* W_k      = (const float*)d_in[9];
    const float* b_k      = (const float*)d_in[10];
    const float* W_v      = (const float*)d_in[11];
    const float* b_v      = (const float*)d_in[12];
    const float* W_o      = (const float*)d_in[13];
    const float* b_o      = (const float*)d_in[14];

    char* ws = (char*)d_ws;
    unsigned short* feat_t = (unsigned short*)ws; ws += 69206016;   // blocked [1056][8][128][32] bf16
    unsigned short* kv_t   = (unsigned short*)ws; ws += 138412032;  // [135168][8 heads][64] bf16
    float* Foff   = (float*)ws; ws += 34603008;                     // [135168][64]
    float* qcat   = (float*)ws; ws += 9216000;                      // [7200][320] = [q_proj | qWoff]
    float* S      = (float*)ws; ws += 7372800;                      // [8][230400] scrambled
    unsigned short* Wkv = (unsigned short*)ws; ws += 524288;        // blocked [4][8][128][32] bf16
    float* bkv    = (float*)ws; ws += 2048;                         // [512]
    unsigned short* Woffp = (unsigned short*)ws; ws += 65536;       // blocked [8 kt][4096] bf16
    float* Wcat   = (float*)ws; ws += 327680;                       // [320][256] fp32
    float* bcat   = (float*)ws; ws += 1280;                         // [320]

    prep_all<<<512, 256, 0, stream>>>(W_k, b_k, W_v, b_v, W_q, b_q, W_off, b_off,
                                      Wkv, bkv, Woffp, Wcat, bcat);
    transpose_feat<<<dim3(88, 8, 48), 256, 0, stream>>>(features, feat_t);
    // kv_t (bn 0-7, head-interleaved) + Foff (bn 8) : 40KB counted-vmcnt pipeline
    gemm_kv2<<<9504, 256, 0, stream>>>(feat_t, Wkv, Woffp, bkv, kv_t, Foff);
    // qcat = query @ [W_q|W_off]^T + [b_q|b_off] : [7200 x 320]
    gemm_bf16<true, false><<<dim3(113, 5, 1), 256, 0, stream>>>(
        query, 0, Wcat, bcat, qcat, 0, 7200, 320, 256, 256);
    // attention (projection + offset sampling fused in)
    attn_kernel<<<7200, 512, 0, stream>>>(qcat, points, camM, camb, Foff, kv_t, S);
    // out = S @ W_o^T + b_o : [7200 x 256]
    gemm_bf16<true, false><<<dim3(113, 4, 1), 256, 0, stream>>>(
        S, 0, W_o, b_o, d_out, 0, 7200, 256, 256, 256);
}

// Round 17
// 228.291 us; speedup vs baseline: 1.1377x; 1.0208x over previous
//
#include <hip/hip_runtime.h>

typedef __attribute__((ext_vector_type(4))) float f32x4;
typedef __attribute__((ext_vector_type(8))) short bf16x8;
typedef __attribute__((ext_vector_type(4))) unsigned int u32x4;

__device__ __forceinline__ unsigned short f2bf(float f) {
    union { float f; unsigned int u; } x; x.f = f;
    unsigned int u = x.u;
    return (unsigned short)((u + 0x7FFFu + ((u >> 16) & 1u)) >> 16);
}
__device__ __forceinline__ float bf2f(unsigned short b) {
    union { unsigned int u; float f; } x; x.u = ((unsigned int)b) << 16;
    return x.f;
}
__device__ __forceinline__ float u2f(unsigned int u) {
    union { unsigned int u; float f; } x; x.u = u; return x.f;
}

// blocked layout (row r, ch k), 128-row blocks: ((r>>7)*8 + (k>>5))*4096 + (r&127)*32 + (k&31)
// LDS tiles: 16B-chunk XOR swizzle, chunk c of row r at c ^ ((r>>1)&3); staging pre-swizzles
// the per-lane GLOBAL source (LDS dest linear); reads use chunk lk ^ ((lrow>>1)&3).
// kv_t layout: [pixel][head][K ch 0-31 | V ch 0-31] bf16 (head-interleaved, 128B per head).

// ---------------- prep (merged): Wkv blocked bf16, Woff blocked bf16, Wcat=[Wq|Woff] fp32 ----------------
__global__ void prep_all(const float* __restrict__ Wk, const float* __restrict__ bk,
                         const float* __restrict__ Wv, const float* __restrict__ bv,
                         const float* __restrict__ Wq, const float* __restrict__ bq,
                         const float* __restrict__ Woff, const float* __restrict__ boff,
                         unsigned short* __restrict__ Wkv, float* __restrict__ bkv,
                         unsigned short* __restrict__ Woffp,
                         float* __restrict__ Wcat, float* __restrict__ bcat) {
    int i = blockIdx.x * 256 + threadIdx.x;   // grid 512*256 = 131072
    if (i < 512 * 256) {
        int n = i >> 8, k = i & 255;
        float v = (n < 256) ? Wk[i] : Wv[i - 65536];
        Wkv[((size_t)(n >> 7) * 8 + (k >> 5)) * 4096 + (n & 127) * 32 + (k & 31)] = f2bf(v);
    }
    if (i < 512) bkv[i] = (i < 256) ? bk[i] : bv[i - 256];
    if (i < 64 * 256) {
        int n = i >> 8, k = i & 255;
        Woffp[(size_t)(k >> 5) * 4096 + n * 32 + (k & 31)] = f2bf(Woff[i]);
    }
    if (i < 320 * 256) Wcat[i] = (i < 65536) ? Wq[i] : Woff[i - 65536];
    if (i < 320) bcat[i] = (i < 256) ? bq[i] : boff[i - 256];
}

// ---------------- transpose features [48][256][2816] -> bf16 blocked ----------------
__global__ __launch_bounds__(256) void transpose_feat(const float* __restrict__ src,
                                                      unsigned short* __restrict__ dst) {
    __shared__ float tile[32][33];
    int img = blockIdx.z;
    int p0 = blockIdx.x * 32;   // pixel
    int d0 = blockIdx.y * 32;   // channel
    int tx = threadIdx.x & 31, ty = threadIdx.x >> 5;
    const float* s = src + (size_t)img * 256 * 2816;
#pragma unroll
    for (int i = 0; i < 4; i++) tile[ty + 8 * i][tx] = s[(size_t)(d0 + ty + 8 * i) * 2816 + p0 + tx];
    __syncthreads();
    int m = img * 2816 + p0;
    unsigned short* o = dst + ((size_t)(m >> 7) * 8 + (d0 >> 5)) * 4096 + (m & 127) * 32;
#pragma unroll
    for (int i = 0; i < 4; i++) o[(ty + 8 * i) * 32 + tx] = f2bf(tile[tx][ty + 8 * i]);
}

// ---------------- kv+off projection: K+V paired cols (full-line writes), counted-vmcnt ----------------
// bn' 0..3: block computes 128 px x 128 cols = K-slab bn' (64) + V-slab bn'+4 (64)
//           = heads 2bn',2bn'+1 complete [K|V] -> 256B contiguous full-line stores.
// bn' 4   : Foff[135168][64] fp32 = A @ Woff^T (no bias; dummy V operand for uniform code).
// Block = 128 px; 4 waves, wave-private A staging. B half (32KB, kt0-3) staged, re-staged
// mid-loop. A ring: 3 slots x 8KB, depth-2, per-wave s_waitcnt vmcnt(N). LDS 56KB.
__global__ __launch_bounds__(256) void gemm_kv2(
    const unsigned short* __restrict__ A,
    const unsigned short* __restrict__ Wkv,
    const unsigned short* __restrict__ Woffp,
    const float* __restrict__ bias,
    unsigned short* __restrict__ C,
    float* __restrict__ Foff) {
    __shared__ __align__(16) unsigned short Bl[16384];    // 32KB: [kt-local][64K r|64V r][32c] (swizzled)
    __shared__ __align__(16) unsigned short Ar[3][4096];  // ring: [slot][128r][32c] (swizzled)

    const int tid = threadIdx.x, lane = tid & 63, w = tid >> 6;
    const int lrow = lane & 15, lk = lane >> 4;
    const int lsw = (lane >> 2) * 32 + (((lane & 3) ^ ((lane >> 3) & 3)) * 8);
    const int ckx = ((lrow >> 1) & 3);    // read-side chunk xor
    const int bid = blockIdx.x;
    const int wgid = (bid & 7) * 660 + (bid >> 3);   // XCD swizzle (5280 = 8*660)
    const int chunk = wgid / 5, bn = wgid % 5;       // chunk: m-block 0..1055, bn: 0..4

    const unsigned short* A0 = A + (size_t)chunk * 32768;
    const unsigned short* BbK = (bn < 4)
        ? Wkv + (size_t)(bn >> 1) * 32768 + (bn & 1) * 2048
        : Woffp;
    const unsigned short* BbV = (bn < 4)
        ? Wkv + (size_t)((bn + 4) >> 1) * 32768 + ((bn + 4) & 1) * 2048
        : Woffp;                                     // dummy (keeps load counts uniform)
    const int wof = w * 1024;   // wave-private 32-row region (shorts) within a slot

    // stage B half (32KB): wave w stages kt-local w: 4x1KB K rows + 4x1KB V rows
#define STAGE_B(HALF)                                                                        \
    {                                                                                        \
        _Pragma("unroll")                                                                    \
        for (int i = 0; i < 4; ++i) {                                                        \
            __builtin_amdgcn_global_load_lds(                                                \
                (const __attribute__((address_space(1))) unsigned int*)(BbK + ((HALF) * 4 + w) * 4096 + i * 512 + lsw), \
                (__attribute__((address_space(3))) unsigned int*)&Bl[w * 4096 + i * 512], 16, 0, 0);                    \
        }                                                                                    \
        _Pragma("unroll")                                                                    \
        for (int i = 0; i < 4; ++i) {                                                        \
            __builtin_amdgcn_global_load_lds(                                                \
                (const __attribute__((address_space(1))) unsigned int*)(BbV + ((HALF) * 4 + w) * 4096 + i * 512 + lsw), \
                (__attribute__((address_space(3))) unsigned int*)&Bl[w * 4096 + 2048 + i * 512], 16, 0, 0);             \
        }                                                                                    \
    }

#define STAGE_STEP(S)                                                                        \
    {                                                                                        \
        __builtin_amdgcn_global_load_lds(                                                    \
            (const __attribute__((address_space(1))) unsigned int*)(A0 + (S) * 4096 + wof + lsw),        \
            (__attribute__((address_space(3))) unsigned int*)&Ar[(S) % 3][wof], 16, 0, 0);   \
        __builtin_amdgcn_global_load_lds(                                                    \
            (const __attribute__((address_space(1))) unsigned int*)(A0 + (S) * 4096 + wof + 512 + lsw),  \
            (__attribute__((address_space(3))) unsigned int*)&Ar[(S) % 3][wof + 512], 16, 0, 0);         \
    }

    STAGE_B(0)
    STAGE_STEP(0) STAGE_STEP(1)
    __syncthreads();   // drains: B half0 + A0,A1 resident

    f32x4 acc[2][8] = {};   // [i][j]; j 0-3 = K slab, j 4-7 = V slab

    // COMP: wait A(S) -> ds_read frags -> drain own ds_reads -> stage A(S+2) -> 16 MFMAs
#define COMP_STEP(S, NW)                                                                     \
    {                                                                                        \
        asm volatile("s_waitcnt vmcnt(%0)" :: "i"(NW) : "memory");                           \
        bf16x8 bfr[8], af[2];                                                                \
        _Pragma("unroll") for (int j = 0; j < 4; ++j)                                        \
            bfr[j] = *(const bf16x8*)&Bl[((S) & 3) * 4096 + (j * 16 + lrow) * 32 + (lk ^ ckx) * 8];          \
        _Pragma("unroll") for (int j = 0; j < 4; ++j)                                        \
            bfr[4 + j] = *(const bf16x8*)&Bl[((S) & 3) * 4096 + 2048 + (j * 16 + lrow) * 32 + (lk ^ ckx) * 8]; \
        _Pragma("unroll") for (int i = 0; i < 2; ++i)                                        \
            af[i] = *(const bf16x8*)&Ar[(S) % 3][wof + i * 512 + lrow * 32 + (lk ^ ckx) * 8];\
        if ((S) + 2 < 8) {                                                                   \
            asm volatile("s_waitcnt lgkmcnt(0)" ::: "memory");                               \
            STAGE_STEP((S) + 2)                                                              \
        }                                                                                    \
        _Pragma("unroll") for (int i = 0; i < 2; ++i)                                        \
            _Pragma("unroll") for (int j = 0; j < 8; ++j)                                    \
                acc[i][j] = __builtin_amdgcn_mfma_f32_16x16x32_bf16(af[i], bfr[j], acc[i][j], 0, 0, 0); \
    }

    COMP_STEP(0, 4) COMP_STEP(1, 2) COMP_STEP(2, 2) COMP_STEP(3, 2)
    __syncthreads();          // all waves done reading B half0 (drains A4,A5 too)
    STAGE_B(1)
    __syncthreads();          // B half1 resident
    COMP_STEP(4, 4) COMP_STEP(5, 2) COMP_STEP(6, 2) COMP_STEP(7, 0)
#undef COMP_STEP
#undef STAGE_STEP
#undef STAGE_B

    if (bn < 4) {
        // epilogue: acc -> Cl[128 px][128 cols] bf16 (32KB, aliases Bl) -> 256B full-line stores
        unsigned short* Cl = &Bl[0];
        __syncthreads();
#pragma unroll
        for (int j = 0; j < 8; ++j) {
            float bs = (j < 4) ? bias[bn * 64 + j * 16 + lrow]
                               : bias[(bn + 4) * 64 + (j - 4) * 16 + lrow];
#pragma unroll
            for (int i = 0; i < 2; ++i)
#pragma unroll
                for (int jj = 0; jj < 4; ++jj)
                    Cl[(w * 32 + i * 16 + lk * 4 + jj) * 128 + j * 16 + lrow] =
                        f2bf(acc[i][j][jj] + bs);
        }
        __syncthreads();
        // dst chunk d (16 per px, 8 shorts each): [h0K(0-3) h0V(4-7) h1K(8-11) h1V(12-15)]
        // src chunk s in Cl: [K0(0-3) K1(4-7) V0(8-11) V1(12-15)]
#pragma unroll
        for (int it = 0; it < 8; ++it) {
            int idx = it * 256 + tid;
            int px = idx >> 4, d = idx & 15;
            int s = (d < 4) ? d : (d < 8) ? d + 4 : (d < 12) ? d - 4 : d;
            *(f32x4*)(C + (size_t)(chunk * 128 + px) * 512 + bn * 128 + d * 8) =
                *(const f32x4*)&Cl[px * 128 + s * 8];
        }
    } else {
        // Foff epilogue: fp32 direct stores (no bias); only K-slab accs are meaningful
#pragma unroll
        for (int i = 0; i < 2; ++i)
#pragma unroll
            for (int j = 0; j < 4; ++j)
#pragma unroll
                for (int jj = 0; jj < 4; ++jj) {
                    int m = chunk * 128 + w * 32 + i * 16 + lk * 4 + jj;
                    Foff[(size_t)m * 64 + j * 16 + lrow] = acc[i][j][jj];
                }
    }
}

// ---------------- split-bf16 MFMA GEMM (fp32 A/B in): C = A@B^T + bias ----------------
template <bool SPLIT, bool C_BF16>
__global__ __launch_bounds__(256) void gemm_bf16(
    const float* __restrict__ A, long long aBatch,
    const float* __restrict__ B, const float* __restrict__ bias,
    void* __restrict__ Cv, long long cBatch,
    int M, int N, int K, int lda) {
    __shared__ __align__(16) unsigned short Ah[64][40];
    __shared__ __align__(16) unsigned short Bh[64][40];
    __shared__ __align__(16) unsigned short Al[(SPLIT ? 64 : 1)][40];
    __shared__ __align__(16) unsigned short Bl[(SPLIT ? 64 : 1)][40];

    const int tid = threadIdx.x;
    const int m0 = blockIdx.x * 64, n0 = blockIdx.y * 64;
    const int batch = blockIdx.z;
    const float* Ab = A + (size_t)batch * aBatch;
    const int lane = tid & 63, wave = tid >> 6;
    const int wr = wave & 1, wc = wave >> 1;
    const int lrow = lane & 15, lk = lane >> 4;

    f32x4 acc[2][2] = {};

    for (int kt = 0; kt < K; kt += 32) {
        if (kt) __syncthreads();
        {
            int c4 = (tid & 7) * 4;
#pragma unroll
            for (int rep = 0; rep < 2; rep++) {
                int r = (tid >> 3) + rep * 32;
                int m = m0 + r; if (m >= M) m = M - 1;
                f32x4 v = *(const f32x4*)(Ab + (size_t)m * lda + kt + c4);
#pragma unroll
                for (int q = 0; q < 4; q++) {
                    unsigned short h = f2bf(v[q]);
                    Ah[r][c4 + q] = h;
                    if (SPLIT) Al[r][c4 + q] = f2bf(v[q] - bf2f(h));
                }
            }
        }
        {
            int c4 = (tid & 7) * 4;
#pragma unroll
            for (int rep = 0; rep < 2; rep++) {
                int r = (tid >> 3) + rep * 32;
                f32x4 v = *(const f32x4*)(B + (size_t)(n0 + r) * K + kt + c4);
#pragma unroll
                for (int q = 0; q < 4; q++) {
                    unsigned short h = f2bf(v[q]);
                    Bh[r][c4 + q] = h;
                    if (SPLIT) Bl[r][c4 + q] = f2bf(v[q] - bf2f(h));
                }
            }
        }
        __syncthreads();

        bf16x8 a_h[2], b_h[2], a_l[2], b_l[2];
#pragma unroll
        for (int i = 0; i < 2; i++) {
            a_h[i] = *(const bf16x8*)&Ah[wr * 32 + i * 16 + lrow][lk * 8];
            b_h[i] = *(const bf16x8*)&Bh[wc * 32 + i * 16 + lrow][lk * 8];
            if (SPLIT) {
                a_l[i] = *(const bf16x8*)&Al[wr * 32 + i * 16 + lrow][lk * 8];
                b_l[i] = *(const bf16x8*)&Bl[wc * 32 + i * 16 + lrow][lk * 8];
            }
        }
#pragma unroll
        for (int i = 0; i < 2; i++)
#pragma unroll
            for (int j = 0; j < 2; j++) {
                acc[i][j] = __builtin_amdgcn_mfma_f32_16x16x32_bf16(a_h[i], b_h[j], acc[i][j], 0, 0, 0);
                if (SPLIT) {
                    acc[i][j] = __builtin_amdgcn_mfma_f32_16x16x32_bf16(a_h[i], b_l[j], acc[i][j], 0, 0, 0);
                    acc[i][j] = __builtin_amdgcn_mfma_f32_16x16x32_bf16(a_l[i], b_h[j], acc[i][j], 0, 0, 0);
                }
            }
    }

#pragma unroll
    for (int i = 0; i < 2; i++)
#pragma unroll
        for (int j = 0; j < 2; j++) {
            int n = n0 + wc * 32 + j * 16 + lrow;
            float bs = bias[n];
#pragma unroll
            for (int jj = 0; jj < 4; jj++) {
                int m = m0 + wr * 32 + i * 16 + lk * 4 + jj;
                if (m < M) {
                    float val = acc[i][j][jj] + bs;
                    if (C_BF16)
                        ((unsigned short*)Cv)[(size_t)batch * cBatch + (size_t)m * N + n] = f2bf(val);
                    else
                        ((float*)Cv)[(size_t)batch * cBatch + (size_t)m * N + n] = val;
                }
            }
        }
}

// ---------------- fused deformable attention (projection + offsets fused in) ----------------
__global__ __launch_bounds__(512) void attn_kernel(
    const float* __restrict__ qcat, const float* __restrict__ points,
    const float* __restrict__ camM, const float* __restrict__ camb,
    const float* __restrict__ Foff, const unsigned short* __restrict__ kv_t,
    float* __restrict__ S) {
    int bk = blockIdx.x;            // b*900 + k
    int b = bk / 900, k = bk % 900;
    int h = threadIdx.x >> 6;       // wave = head
    int lane = threadIdx.x & 63;

    __shared__ __align__(16) float        ldsW[8][24][4];
    __shared__ __align__(16) unsigned int ldsI[8][24][4];
    __shared__ float ldsL[8][24];

    if (lane < 24) {
        int cam = lane >> 2, p = lane & 3;
        float pt0 = points[(size_t)bk * 3 + 0];
        float pt1 = points[(size_t)bk * 3 + 1];
        float pt2 = points[(size_t)bk * 3 + 2];
        const float* M = camM + cam * 6;
        float s0 = M[0] * pt0 + M[1] * pt1 + M[2] * pt2 + camb[cam * 2 + 0];
        float s1 = M[3] * pt0 + M[4] * pt1 + M[5] * pt2 + camb[cam * 2 + 1];
        float px0 = (1.f / (1.f + expf(-s0))) * 32.f;
        float px1 = (1.f / (1.f + expf(-s1))) * 88.f;
        {
            float gxb = 2.f * px0 / 32.f - 1.f, gyb = 2.f * px1 / 88.f - 1.f;
            float ixb = (gxb + 1.f) * 0.5f * 87.f;
            float iyb = (gyb + 1.f) * 0.5f * 31.f;
            float xb0 = floorf(ixb), yb0 = floorf(iyb), xb1 = xb0 + 1.f, yb1 = yb0 + 1.f;
            float wxb1 = ixb - xb0, wxb0 = xb1 - ixb, wyb1 = iyb - yb0, wyb0 = yb1 - iyb;
            float mb00 = (xb0 >= 0.f && xb0 <= 87.f && yb0 >= 0.f && yb0 <= 31.f) ? 1.f : 0.f;
            float mb01 = (xb1 >= 0.f && xb1 <= 87.f && yb0 >= 0.f && yb0 <= 31.f) ? 1.f : 0.f;
            float mb10 = (xb0 >= 0.f && xb0 <= 87.f && yb1 >= 0.f && yb1 <= 31.f) ? 1.f : 0.f;
            float mb11 = (xb1 >= 0.f && xb1 <= 87.f && yb1 >= 0.f && yb1 <= 31.f) ? 1.f : 0.f;
            float wb00 = wxb0 * wyb0 * mb00, wb01 = wxb1 * wyb0 * mb01;
            float wb10 = wxb0 * wyb1 * mb10, wb11 = wxb1 * wyb1 * mb11;
            int xib0 = (int)fminf(fmaxf(xb0, 0.f), 87.f);
            int xib1 = (int)fminf(fmaxf(xb1, 0.f), 87.f);
            int yib0 = (int)fminf(fmaxf(yb0, 0.f), 31.f);
            int yib1 = (int)fminf(fmaxf(yb1, 0.f), 31.f);
            size_t base = (size_t)(cam * 8 + b) * 2816;
            const float* f00 = Foff + (base + yib0 * 88 + xib0) * 64;
            const float* f01 = Foff + (base + yib0 * 88 + xib1) * 64;
            const float* f10 = Foff + (base + yib1 * 88 + xib0) * 64;
            const float* f11 = Foff + (base + yib1 * 88 + xib1) * 64;
            int j0 = (h * 4 + p) * 2;
            float o0 = qcat[(size_t)bk * 320 + 256 + j0]
                     + wb00 * f00[j0] + wb01 * f01[j0] + wb10 * f10[j0] + wb11 * f11[j0];
            float o1 = qcat[(size_t)bk * 320 + 256 + j0 + 1]
                     + wb00 * f00[j0 + 1] + wb01 * f01[j0 + 1] + wb10 * f10[j0 + 1] + wb11 * f11[j0 + 1];
            float pc0 = px0 + o0 * (1.f / 32.f);
            float pc1 = px1 + o1 * (1.f / 88.f);
            float gx = 2.f * (pc0 * (1.f / 32.f)) - 1.f;
            float gy = 2.f * (pc1 * (1.f / 88.f)) - 1.f;
            float ix = (gx + 1.f) * 0.5f * 87.f;
            float iy = (gy + 1.f) * 0.5f * 31.f;
            float x0 = floorf(ix), y0 = floorf(iy), x1 = x0 + 1.f, y1 = y0 + 1.f;
            float wx1 = ix - x0, wx0 = x1 - ix, wy1 = iy - y0, wy0 = y1 - iy;
            float m00 = (x0 >= 0.f && x0 <= 87.f && y0 >= 0.f && y0 <= 31.f) ? 1.f : 0.f;
            float m01 = (x1 >= 0.f && x1 <= 87.f && y0 >= 0.f && y0 <= 31.f) ? 1.f : 0.f;
            float m10 = (x0 >= 0.f && x0 <= 87.f && y1 >= 0.f && y1 <= 31.f) ? 1.f : 0.f;
            float m11 = (x1 >= 0.f && x1 <= 87.f && y1 >= 0.f && y1 <= 31.f) ? 1.f : 0.f;
            int xi0 = (int)fminf(fmaxf(x0, 0.f), 87.f);
            int xi1 = (int)fminf(fmaxf(x1, 0.f), 87.f);
            int yi0 = (int)fminf(fmaxf(y0, 0.f), 31.f);
            int yi1 = (int)fminf(fmaxf(y1, 0.f), 31.f);
            unsigned int img = (unsigned int)(cam * 8 + b) * 2816u;
            ldsW[h][lane][0] = wx0 * wy0 * m00;
            ldsW[h][lane][1] = wx1 * wy0 * m01;
            ldsW[h][lane][2] = wx0 * wy1 * m10;
            ldsW[h][lane][3] = wx1 * wy1 * m11;
            ldsI[h][lane][0] = (img + yi0 * 88 + xi0) * 1024u;
            ldsI[h][lane][1] = (img + yi0 * 88 + xi1) * 1024u;
            ldsI[h][lane][2] = (img + yi1 * 88 + xi0) * 1024u;
            ldsI[h][lane][3] = (img + yi1 * 88 + xi1) * 1024u;
        }
    }
    __syncthreads();

    const int p8 = lane >> 3, dlane = lane & 7;
    const int chB = h * 128 + dlane * 16;    // byte offset within pixel row
    const char* kvb = (const char*)kv_t;

    f32x4 qa = *(const f32x4*)(qcat + (size_t)bk * 320 + h * 32 + (dlane & 3) * 8);
    f32x4 qb = *(const f32x4*)(qcat + (size_t)bk * 320 + h * 32 + (dlane & 3) * 8 + 4);

    float vr[3][8];
    const float inv_sqrt = 0.17677669529663687f;
#pragma unroll
    for (int it = 0; it < 3; ++it) {
        int l = it * 8 + p8;
        f32x4 w = *(const f32x4*)ldsW[h][l];
        unsigned int i0 = ldsI[h][l][0], i1 = ldsI[h][l][1];
        unsigned int i2 = ldsI[h][l][2], i3 = ldsI[h][l][3];
        u32x4 u0 = *(const u32x4*)(kvb + i0 + chB);
        u32x4 u1 = *(const u32x4*)(kvb + i1 + chB);
        u32x4 u2 = *(const u32x4*)(kvb + i2 + chB);
        u32x4 u3 = *(const u32x4*)(kvb + i3 + chB);
#pragma unroll
        for (int q = 0; q < 4; ++q) {
            vr[it][2 * q] = w[0] * u2f(u0[q] << 16) + w[1] * u2f(u1[q] << 16)
                          + w[2] * u2f(u2[q] << 16) + w[3] * u2f(u3[q] << 16);
            vr[it][2 * q + 1] = w[0] * u2f(u0[q] & 0xFFFF0000u) + w[1] * u2f(u1[q] & 0xFFFF0000u)
                              + w[2] * u2f(u2[q] & 0xFFFF0000u) + w[3] * u2f(u3[q] & 0xFFFF0000u);
        }
        float t = qa[0] * vr[it][0] + qa[1] * vr[it][1] + qa[2] * vr[it][2] + qa[3] * vr[it][3]
                + qb[0] * vr[it][4] + qb[1] * vr[it][5] + qb[2] * vr[it][6] + qb[3] * vr[it][7];
        t += __shfl_xor(t, 1);
        t += __shfl_xor(t, 2);
        if (dlane == 0) ldsL[h][l] = t * inv_sqrt;
    }
    __syncthreads();

    float mx = -1e30f;
#pragma unroll
    for (int l = 0; l < 24; l++) mx = fmaxf(mx, ldsL[h][l]);
    float ssum = 0.f;
    float at3[3];
#pragma unroll
    for (int l = 0; l < 24; l++) {
        float e = __expf(ldsL[h][l] - mx);
        ssum += e;
        if ((l & 7) == p8) at3[l >> 3] = e;
    }
    float inv = 1.f / ssum;

    float o[8];
#pragma unroll
    for (int j = 0; j < 8; ++j)
        o[j] = at3[0] * vr[0][j] + at3[1] * vr[1][j] + at3[2] * vr[2][j];
#pragma unroll
    for (int j = 0; j < 8; ++j) {
        o[j] += __shfl_xor(o[j], 8);
        o[j] += __shfl_xor(o[j], 16);
        o[j] += __shfl_xor(o[j], 32);
    }
    if (p8 == 0 && dlane >= 4) {
        int d0 = (dlane - 4) * 8;
        f32x4 v0, v1;
        v0[0] = o[0] * inv; v0[1] = o[1] * inv; v0[2] = o[2] * inv; v0[3] = o[3] * inv;
        v1[0] = o[4] * inv; v1[1] = o[5] * inv; v1[2] = o[6] * inv; v1[3] = o[7] * inv;
        float* dst = &S[(size_t)b * 230400 + (size_t)h * 28800 + k * 32 + d0];
        *(f32x4*)dst = v0;
        *(f32x4*)(dst + 4) = v1;
    }
}

extern "C" void kernel_launch(void* const* d_in, const int* in_sizes, int n_in,
                              void* d_out, int out_size, void* d_ws, size_t ws_size,
                              hipStream_t stream) {
    const float* query    = (const float*)d_in[0];
    const float* points   = (const float*)d_in[1];
    const float* features = (const float*)d_in[2];
    const float* camM     = (const float*)d_in[3];
    const float* camb     = (const float*)d_in[4];
    const float* W_off    = (const float*)d_in[5];
    const float* b_off    = (const float*)d_in[6];
    const float* W_q      = (const float*)d_in[7];
    const float* b_q      = (const float*)d_in[8];
    const float* W_k      = (const float*)d_in[9];
    const float* b_k      = (const float*)d_in[10];
    const float* W_v      = (const float*)d_in[11];
    const float* b_v      = (const float*)d_in[12];
    const float* W_o      = (const float*)d_in[13];
    const float* b_o      = (const float*)d_in[14];

    char* ws = (char*)d_ws;
    unsigned short* feat_t = (unsigned short*)ws; ws += 69206016;   // blocked [1056][8][128][32] bf16
    unsigned short* kv_t   = (unsigned short*)ws; ws += 138412032;  // [135168][8 heads][64] bf16
    float* Foff   = (float*)ws; ws += 34603008;                     // [135168][64]
    float* qcat   = (float*)ws; ws += 9216000;                      // [7200][320] = [q_proj | qWoff]
    float* S      = (float*)ws; ws += 7372800;                      // [8][230400] scrambled
    unsigned short* Wkv = (unsigned short*)ws; ws += 524288;        // blocked [4][8][128][32] bf16
    float* bkv    = (float*)ws; ws += 2048;                         // [512]
    unsigned short* Woffp = (unsigned short*)ws; ws += 65536;       // blocked [8 kt][4096] bf16
    float* Wcat   = (float*)ws; ws += 327680;                       // [320][256] fp32
    float* bcat   = (float*)ws; ws += 1280;                         // [320]

    prep_all<<<512, 256, 0, stream>>>(W_k, b_k, W_v, b_v, W_q, b_q, W_off, b_off,
                                      Wkv, bkv, Woffp, Wcat, bcat);
    transpose_feat<<<dim3(88, 8, 48), 256, 0, stream>>>(features, feat_t);
    // kv_t (bn 0-3, K+V paired full-line stores) + Foff (bn 4)
    gemm_kv2<<<5280, 256, 0, stream>>>(feat_t, Wkv, Woffp, bkv, kv_t, Foff);
    // qcat = query @ [W_q|W_off]^T + [b_q|b_off] : [7200 x 320]
    gemm_bf16<true, false><<<dim3(113, 5, 1), 256, 0, stream>>>(
        query, 0, Wcat, bcat, qcat, 0, 7200, 320, 256, 256);
    // attention (projection + offset sampling fused in)
    attn_kernel<<<7200, 512, 0, stream>>>(qcat, points, camM, camb, Foff, kv_t, S);
    // out = S @ W_o^T + b_o : [7200 x 256]
    gemm_bf16<true, false><<<dim3(113, 4, 1), 256, 0, stream>>>(
        S, 0, W_o, b_o, d_out, 0, 7200, 256, 256, 256);
}